// Round 1
// baseline (2053.234 us; speedup 1.0000x reference)
//
#include <hip/hip_runtime.h>
#include <hip/hip_bf16.h>

// ---------------------------------------------------------------------------
// GAT 2-layer pipeline, fp32, atomic-based segment softmax + aggregation.
// N=50000 nodes, E edges (+N self-loops appended), layer1 H=4 C=32, layer2 H=1 C=64.
// ---------------------------------------------------------------------------

#define NNODES 50000

// monotone float<->uint order mapping for atomicMax on floats (incl. negatives)
__device__ __forceinline__ unsigned int ford(float f) {
    unsigned int u = __float_as_uint(f);
    return (u & 0x80000000u) ? ~u : (u | 0x80000000u);
}
__device__ __forceinline__ float unford(unsigned int u) {
    return (u & 0x80000000u) ? __uint_as_float(u & 0x7fffffffu) : __uint_as_float(~u);
}

// Y[nrows,COLS] = X[nrows,128] @ W[128,COLS]; W staged in LDS once per block.
template <int COLS>
__global__ __launch_bounds__(256) void gemm_k(const float* __restrict__ X,
                                              const float* __restrict__ W,
                                              float* __restrict__ Y, int nrows) {
    constexpr int K = 128;
    constexpr int CPT = 4;                    // cols per thread
    constexpr int ROWS = 256 * CPT / COLS;    // 8 (COLS=128) or 16 (COLS=64)
    constexpr int CG = COLS / CPT;            // col groups: 32 or 16
    __shared__ float sW[K * COLS];
    __shared__ float sX[ROWS][K];
    for (int i = threadIdx.x; i < K * COLS; i += 256) sW[i] = W[i];
    const int c0 = threadIdx.x % CG;
    const int r  = threadIdx.x / CG;
    for (int rb = blockIdx.x * ROWS; rb < nrows; rb += gridDim.x * ROWS) {
        __syncthreads();
        for (int i = threadIdx.x; i < ROWS * K; i += 256) {
            int rr = i / K, kk = i % K;
            int row = rb + rr;
            sX[rr][kk] = (row < nrows) ? X[(size_t)row * K + kk] : 0.0f;
        }
        __syncthreads();
        float acc[CPT] = {0.0f, 0.0f, 0.0f, 0.0f};
#pragma unroll 8
        for (int k = 0; k < K; ++k) {
            float xv = sX[r][k];
#pragma unroll
            for (int j = 0; j < CPT; ++j)
                acc[j] += xv * sW[k * COLS + c0 + j * CG];
        }
        int row = rb + r;
        if (row < nrows) {
#pragma unroll
            for (int j = 0; j < CPT; ++j)
                Y[(size_t)row * COLS + c0 + j * CG] = acc[j];
        }
    }
}

// a_src[n,h] = sum_c xw[n,h,c]*att_src[h,c]; one thread per (n,h)
template <int H, int C>
__global__ void attn_scores_k(const float* __restrict__ xw,
                              const float* __restrict__ atts,
                              const float* __restrict__ attd,
                              float* __restrict__ a_s, float* __restrict__ a_d,
                              int NH) {
    int i = blockIdx.x * blockDim.x + threadIdx.x;  // i = n*H + h
    if (i >= NH) return;
    const int h = i % H;
    const float* row = xw + (size_t)i * C;
    const float* ps = atts + h * C;
    const float* pd = attd + h * C;
    float as = 0.0f, ad = 0.0f;
#pragma unroll
    for (int c = 0; c < C; ++c) {
        float v = row[c];
        as += v * ps[c];
        ad += v * pd[c];
    }
    a_s[i] = as;
    a_d[i] = ad;
}

template <int H>
__global__ void edge_max_k(const int* __restrict__ esrc, const int* __restrict__ edst,
                           int E, int Nn,
                           const float* __restrict__ a_s, const float* __restrict__ a_d,
                           unsigned int* __restrict__ mo) {
    int e = blockIdx.x * blockDim.x + threadIdx.x;
    int Etot = E + Nn;
    if (e >= Etot) return;
    int s = (e < E) ? esrc[e] : (e - E);
    int d = (e < E) ? edst[e] : (e - E);
#pragma unroll
    for (int h = 0; h < H; ++h) {
        float v = a_s[s * H + h] + a_d[d * H + h];
        v = (v > 0.0f) ? v : 0.2f * v;
        atomicMax(&mo[d * H + h], ford(v));
    }
}

template <int H>
__global__ void edge_sum_k(const int* __restrict__ esrc, const int* __restrict__ edst,
                           int E, int Nn,
                           const float* __restrict__ a_s, const float* __restrict__ a_d,
                           const unsigned int* __restrict__ mo,
                           float* __restrict__ ssum) {
    int e = blockIdx.x * blockDim.x + threadIdx.x;
    int Etot = E + Nn;
    if (e >= Etot) return;
    int s = (e < E) ? esrc[e] : (e - E);
    int d = (e < E) ? edst[e] : (e - E);
#pragma unroll
    for (int h = 0; h < H; ++h) {
        float v = a_s[s * H + h] + a_d[d * H + h];
        v = (v > 0.0f) ? v : 0.2f * v;
        float m = unford(mo[d * H + h]);
        atomicAdd(&ssum[d * H + h], __expf(v - m));
    }
}

// one wave (64 lanes) per edge; lanes sweep the H*C channels
template <int H, int C>
__global__ void edge_agg_k(const int* __restrict__ esrc, const int* __restrict__ edst,
                           int E, int Nn,
                           const float* __restrict__ xw,
                           const float* __restrict__ a_s, const float* __restrict__ a_d,
                           const unsigned int* __restrict__ mo,
                           const float* __restrict__ ssum,
                           float* __restrict__ agg) {
    constexpr int HC = H * C;
    int wave = (blockIdx.x * blockDim.x + threadIdx.x) >> 6;
    int lane = threadIdx.x & 63;
    int Etot = E + Nn;
    if (wave >= Etot) return;
    int s = (wave < E) ? esrc[wave] : (wave - E);
    int d = (wave < E) ? edst[wave] : (wave - E);
#pragma unroll
    for (int c0 = 0; c0 < HC; c0 += 64) {
        int c = c0 + lane;
        int h = c / C;  // compile-time C -> shift
        float v = a_s[s * H + h] + a_d[d * H + h];
        v = (v > 0.0f) ? v : 0.2f * v;
        float m = unford(mo[d * H + h]);
        float alpha = __expf(v - m) / (ssum[d * H + h] + 1e-16f);
        atomicAdd(&agg[(size_t)d * HC + c], alpha * xw[(size_t)s * HC + c]);
    }
}

// h = ELU(BN(agg + b1)) in-place
__global__ void post1_k(float* __restrict__ buf, const float* __restrict__ b1,
                        const float* __restrict__ gamma, const float* __restrict__ beta,
                        const float* __restrict__ mean, const float* __restrict__ var,
                        int total) {
    int i = blockIdx.x * blockDim.x + threadIdx.x;
    if (i >= total) return;
    int c = i & 127;
    float v = buf[i] + b1[c];
    v = (v - mean[c]) * rsqrtf(var[c] + 1e-5f) * gamma[c] + beta[c];
    buf[i] = (v > 0.0f) ? v : (__expf(v) - 1.0f);
}

// out += b2 in-place
__global__ void post2_k(float* __restrict__ buf, const float* __restrict__ b2, int total) {
    int i = blockIdx.x * blockDim.x + threadIdx.x;
    if (i >= total) return;
    buf[i] += b2[i & 63];
}

extern "C" void kernel_launch(void* const* d_in, const int* in_sizes, int n_in,
                              void* d_out, int out_size, void* d_ws, size_t ws_size,
                              hipStream_t stream) {
    const float* x     = (const float*)d_in[0];
    const int*   ei    = (const int*)d_in[1];
    const float* W1    = (const float*)d_in[2];
    const float* as1   = (const float*)d_in[3];
    const float* ad1   = (const float*)d_in[4];
    const float* b1    = (const float*)d_in[5];
    const float* gamma = (const float*)d_in[6];
    const float* beta  = (const float*)d_in[7];
    const float* mean  = (const float*)d_in[8];
    const float* var   = (const float*)d_in[9];
    const float* W2    = (const float*)d_in[10];
    const float* as2   = (const float*)d_in[11];
    const float* ad2   = (const float*)d_in[12];
    const float* b2    = (const float*)d_in[13];
    float* out = (float*)d_out;

    const int N = NNODES;
    const int E = in_sizes[1] / 2;
    const int Etot = E + N;
    const int* esrc = ei;
    const int* edst = ei + E;

    // workspace layout (all sizes multiple of 16 B)
    char* w = (char*)d_ws;
    float* xw1  = (float*)w; w += (size_t)N * 128 * 4;   // 25.6 MB
    float* agg1 = (float*)w; w += (size_t)N * 128 * 4;   // 25.6 MB (becomes h after post1)
    float* xw2  = (float*)w; w += (size_t)N * 64 * 4;    // 12.8 MB
    float* a_s1 = (float*)w; w += (size_t)N * 4 * 4;
    float* a_d1 = (float*)w; w += (size_t)N * 4 * 4;
    unsigned int* m1 = (unsigned int*)w; w += (size_t)N * 4 * 4;
    float* s1   = (float*)w; w += (size_t)N * 4 * 4;
    float* a_s2 = (float*)w; w += (size_t)N * 4;
    float* a_d2 = (float*)w; w += (size_t)N * 4;
    unsigned int* m2 = (unsigned int*)w; w += (size_t)N * 4;
    float* s2   = (float*)w; w += (size_t)N * 4;

    const int TB = 256;
    const int edgeBlocks = (Etot + TB - 1) / TB;
    const int aggBlocks  = (Etot + 3) / 4;  // one 64-lane wave per edge, 4 waves/block

    // ---------------- layer 1 ----------------
    gemm_k<128><<<1024, TB, 0, stream>>>(x, W1, xw1, N);
    attn_scores_k<4, 32><<<(N * 4 + TB - 1) / TB, TB, 0, stream>>>(xw1, as1, ad1, a_s1, a_d1, N * 4);

    hipMemsetAsync(m1, 0, (size_t)N * 4 * 4, stream);   // ord(x) > 0 for all finite x
    hipMemsetAsync(s1, 0, (size_t)N * 4 * 4, stream);
    edge_max_k<4><<<edgeBlocks, TB, 0, stream>>>(esrc, edst, E, N, a_s1, a_d1, m1);
    edge_sum_k<4><<<edgeBlocks, TB, 0, stream>>>(esrc, edst, E, N, a_s1, a_d1, m1, s1);

    hipMemsetAsync(agg1, 0, (size_t)N * 128 * 4, stream);
    edge_agg_k<4, 32><<<aggBlocks, TB, 0, stream>>>(esrc, edst, E, N, xw1, a_s1, a_d1, m1, s1, agg1);

    post1_k<<<(N * 128 + TB - 1) / TB, TB, 0, stream>>>(agg1, b1, gamma, beta, mean, var, N * 128);

    // ---------------- layer 2 ----------------
    gemm_k<64><<<1024, TB, 0, stream>>>(agg1, W2, xw2, N);
    attn_scores_k<1, 64><<<(N + TB - 1) / TB, TB, 0, stream>>>(xw2, as2, ad2, a_s2, a_d2, N);

    hipMemsetAsync(m2, 0, (size_t)N * 4, stream);
    hipMemsetAsync(s2, 0, (size_t)N * 4, stream);
    edge_max_k<1><<<edgeBlocks, TB, 0, stream>>>(esrc, edst, E, N, a_s2, a_d2, m2);
    edge_sum_k<1><<<edgeBlocks, TB, 0, stream>>>(esrc, edst, E, N, a_s2, a_d2, m2, s2);

    hipMemsetAsync(out, 0, (size_t)N * 64 * 4, stream);
    edge_agg_k<1, 64><<<aggBlocks, TB, 0, stream>>>(esrc, edst, E, N, xw2, a_s2, a_d2, m2, s2, out);

    post2_k<<<(N * 64 + TB - 1) / TB, TB, 0, stream>>>(out, b2, N * 64);
}

// Round 2
// 788.088 us; speedup vs baseline: 2.6053x; 2.6053x over previous
//
#include <hip/hip_runtime.h>
#include <hip/hip_bf16.h>

// ---------------------------------------------------------------------------
// GAT 2-layer pipeline. R2: CSR (counting-sort by dst) + one wave per node
// fused online-softmax + aggregation + epilogue. No float atomics.
// ---------------------------------------------------------------------------

#define NNODES 50000

// Y[nrows,COLS] = X[nrows,128] @ W[128,COLS]; W staged in LDS once per block.
template <int COLS>
__global__ __launch_bounds__(256) void gemm_k(const float* __restrict__ X,
                                              const float* __restrict__ W,
                                              float* __restrict__ Y, int nrows) {
    constexpr int K = 128;
    constexpr int CPT = 4;                    // cols per thread
    constexpr int ROWS = 256 * CPT / COLS;    // 8 (COLS=128) or 16 (COLS=64)
    constexpr int CG = COLS / CPT;            // col groups: 32 or 16
    __shared__ float sW[K * COLS];
    __shared__ float sX[ROWS][K];
    for (int i = threadIdx.x; i < K * COLS; i += 256) sW[i] = W[i];
    const int c0 = threadIdx.x % CG;
    const int r  = threadIdx.x / CG;
    for (int rb = blockIdx.x * ROWS; rb < nrows; rb += gridDim.x * ROWS) {
        __syncthreads();
        for (int i = threadIdx.x; i < ROWS * K; i += 256) {
            int rr = i / K, kk = i % K;
            int row = rb + rr;
            sX[rr][kk] = (row < nrows) ? X[(size_t)row * K + kk] : 0.0f;
        }
        __syncthreads();
        float acc[CPT] = {0.0f, 0.0f, 0.0f, 0.0f};
#pragma unroll 8
        for (int k = 0; k < K; ++k) {
            float xv = sX[r][k];
#pragma unroll
            for (int j = 0; j < CPT; ++j)
                acc[j] += xv * sW[k * COLS + c0 + j * CG];
        }
        int row = rb + r;
        if (row < nrows) {
#pragma unroll
            for (int j = 0; j < CPT; ++j)
                Y[(size_t)row * COLS + c0 + j * CG] = acc[j];
        }
    }
}

// a_src[n,h] = sum_c xw[n,h,c]*att_src[h,c]; one thread per (n,h)
template <int H, int C>
__global__ void attn_scores_k(const float* __restrict__ xw,
                              const float* __restrict__ atts,
                              const float* __restrict__ attd,
                              float* __restrict__ a_s, float* __restrict__ a_d,
                              int NH) {
    int i = blockIdx.x * blockDim.x + threadIdx.x;  // i = n*H + h
    if (i >= NH) return;
    const int h = i % H;
    const float* row = xw + (size_t)i * C;
    const float* ps = atts + h * C;
    const float* pd = attd + h * C;
    float as = 0.0f, ad = 0.0f;
#pragma unroll
    for (int c = 0; c < C; ++c) {
        float v = row[c];
        as += v * ps[c];
        ad += v * pd[c];
    }
    a_s[i] = as;
    a_d[i] = ad;
}

// ----------------------------- CSR build -----------------------------------
__global__ void init_cnt_k(int* __restrict__ cnt, int Nn) {
    int i = blockIdx.x * blockDim.x + threadIdx.x;
    if (i < Nn) cnt[i] = 1;   // self-loop
}

__global__ void hist_k(const int* __restrict__ edst, int E, int* __restrict__ cnt) {
    int e = blockIdx.x * blockDim.x + threadIdx.x;
    if (e < E) atomicAdd(&cnt[edst[e]], 1);
}

__global__ __launch_bounds__(256) void scan1_k(const int* __restrict__ cnt,
                                               int* __restrict__ partial,
                                               int* __restrict__ bsum, int Nn) {
    __shared__ int sA[256];
    int i = blockIdx.x * 256 + threadIdx.x;
    sA[threadIdx.x] = (i < Nn) ? cnt[i] : 0;
    __syncthreads();
    for (int off = 1; off < 256; off <<= 1) {
        int u = (threadIdx.x >= off) ? sA[threadIdx.x - off] : 0;
        __syncthreads();
        sA[threadIdx.x] += u;
        __syncthreads();
    }
    if (i < Nn) partial[i] = sA[threadIdx.x];
    if (threadIdx.x == 255) bsum[blockIdx.x] = sA[255];
}

__global__ __launch_bounds__(256) void scan2_k(int* __restrict__ bsum, int nb) {
    __shared__ int sA[256];
    int t = threadIdx.x;
    sA[t] = (t < nb) ? bsum[t] : 0;
    __syncthreads();
    for (int off = 1; off < 256; off <<= 1) {
        int u = (t >= off) ? sA[t - off] : 0;
        __syncthreads();
        sA[t] += u;
        __syncthreads();
    }
    if (t < nb) bsum[t] = sA[t];
}

__global__ void scan3_k(const int* __restrict__ partial, const int* __restrict__ bsum,
                        int* __restrict__ rowptr, int* __restrict__ cursor, int Nn) {
    int i = blockIdx.x * 256 + threadIdx.x;
    if (i >= Nn) return;
    int b = blockIdx.x;
    int off = (b == 0) ? 0 : bsum[b - 1];
    int incl = partial[i] + off;
    rowptr[i + 1] = incl;
    int excl = incl - ((i < Nn) ? 0 : 0);  // exclusive start for node i
    // exclusive = inclusive - count[i]; easier: cursor from rowptr later.
    (void)excl;
    if (i == 0) rowptr[0] = 0;
    (void)cursor;
}

__global__ void cursor_k(const int* __restrict__ rowptr, int* __restrict__ cursor, int Nn) {
    int i = blockIdx.x * blockDim.x + threadIdx.x;
    if (i < Nn) cursor[i] = rowptr[i];
}

__global__ void scatter_k(const int* __restrict__ esrc, const int* __restrict__ edst,
                          int E, int Nn, int* __restrict__ cursor,
                          int* __restrict__ ssrc_sorted) {
    int e = blockIdx.x * blockDim.x + threadIdx.x;
    int Etot = E + Nn;
    if (e >= Etot) return;
    int s, d;
    if (e < E) { s = esrc[e]; d = edst[e]; }
    else       { s = e - E;   d = e - E; }
    int pos = atomicAdd(&cursor[d], 1);
    ssrc_sorted[pos] = s;
}

// ---------------- fused per-node softmax + aggregation + epilogue ----------
// One 64-lane wave per destination node. EPI: 1 = bias+BN+ELU, 2 = bias only.
template <int H, int C, int EPI>
__global__ __launch_bounds__(256) void node_agg_k(
    const int* __restrict__ rowptr, const int* __restrict__ ssrc,
    const float* __restrict__ xw,
    const float* __restrict__ a_s, const float* __restrict__ a_d,
    const float* __restrict__ bias,
    const float* __restrict__ gamma, const float* __restrict__ beta,
    const float* __restrict__ mean, const float* __restrict__ var,
    float* __restrict__ out, int Nn) {
    constexpr int HC = H * C;
    constexpr int R = HC / 64;
    int n = (blockIdx.x * blockDim.x + threadIdx.x) >> 6;
    int lane = threadIdx.x & 63;
    if (n >= Nn) return;
    const int r0 = rowptr[n];
    const int deg = rowptr[n + 1] - r0;

    float adn[H];
#pragma unroll
    for (int h = 0; h < H; ++h) adn[h] = a_d[n * H + h];

    // pass 1: lane-parallel online softmax (max & sum) per head
    float mx[H], sm[H];
#pragma unroll
    for (int h = 0; h < H; ++h) { mx[h] = -1e30f; sm[h] = 0.0f; }
    for (int j = lane; j < deg; j += 64) {
        int s = ssrc[r0 + j];
#pragma unroll
        for (int h = 0; h < H; ++h) {
            float e = a_s[s * H + h] + adn[h];
            e = (e > 0.0f) ? e : 0.2f * e;
            if (e > mx[h]) {
                sm[h] = sm[h] * __expf(mx[h] - e) + 1.0f;
                mx[h] = e;
            } else {
                sm[h] += __expf(e - mx[h]);
            }
        }
    }
#pragma unroll
    for (int off = 32; off > 0; off >>= 1) {
#pragma unroll
        for (int h = 0; h < H; ++h) {
            float m2 = __shfl_xor(mx[h], off);
            float s2 = __shfl_xor(sm[h], off);
            float m = fmaxf(mx[h], m2);
            sm[h] = sm[h] * __expf(mx[h] - m) + s2 * __expf(m2 - m);
            mx[h] = m;
        }
    }

    // per-register head-selected constants (avoid dynamic array indexing)
    float selM[R], selI[R], selA[R];
#pragma unroll
    for (int k = 0; k < R; ++k) {
        int h = (lane + 64 * k) / C;
        float m = mx[0], iv = sm[0], ad0 = adn[0];
#pragma unroll
        for (int hh = 1; hh < H; ++hh) {
            m   = (h == hh) ? mx[hh]  : m;
            iv  = (h == hh) ? sm[hh]  : iv;
            ad0 = (h == hh) ? adn[hh] : ad0;
        }
        selM[k] = m;
        selI[k] = 1.0f / (iv + 1e-16f);
        selA[k] = ad0;
    }

    // pass 2: sequential over edges, lanes parallel over channels
    float acc[R];
#pragma unroll
    for (int k = 0; k < R; ++k) acc[k] = 0.0f;
    for (int j = 0; j < deg; ++j) {
        int s = ssrc[r0 + j];
        const float* xrow = xw + (size_t)s * HC;
#pragma unroll
        for (int k = 0; k < R; ++k) {
            int c = lane + 64 * k;
            int h = c / C;
            float e = a_s[s * H + h] + selA[k];
            e = (e > 0.0f) ? e : 0.2f * e;
            float alpha = __expf(e - selM[k]) * selI[k];
            acc[k] += alpha * xrow[c];
        }
    }

    size_t base = (size_t)n * HC;
#pragma unroll
    for (int k = 0; k < R; ++k) {
        int c = lane + 64 * k;
        float v = acc[k] + bias[c];
        if (EPI == 1) {
            v = (v - mean[c]) * rsqrtf(var[c] + 1e-5f) * gamma[c] + beta[c];
            v = (v > 0.0f) ? v : (__expf(v) - 1.0f);  // ELU
        }
        out[base + c] = v;
    }
}

extern "C" void kernel_launch(void* const* d_in, const int* in_sizes, int n_in,
                              void* d_out, int out_size, void* d_ws, size_t ws_size,
                              hipStream_t stream) {
    const float* x     = (const float*)d_in[0];
    const int*   ei    = (const int*)d_in[1];
    const float* W1    = (const float*)d_in[2];
    const float* as1   = (const float*)d_in[3];
    const float* ad1   = (const float*)d_in[4];
    const float* b1    = (const float*)d_in[5];
    const float* gamma = (const float*)d_in[6];
    const float* beta  = (const float*)d_in[7];
    const float* mean  = (const float*)d_in[8];
    const float* var   = (const float*)d_in[9];
    const float* W2    = (const float*)d_in[10];
    const float* as2   = (const float*)d_in[11];
    const float* ad2   = (const float*)d_in[12];
    const float* b2    = (const float*)d_in[13];
    float* out = (float*)d_out;

    const int N = NNODES;
    const int E = in_sizes[1] / 2;
    const int Etot = E + N;
    const int* esrc = ei;
    const int* edst = ei + E;

    // workspace layout
    char* w = (char*)d_ws;
    float* xw1  = (float*)w; w += (size_t)N * 128 * 4;   // 25.6 MB
    float* hbuf = (float*)w; w += (size_t)N * 128 * 4;   // 25.6 MB (layer-1 out -> gemm2 in)
    float* xw2  = (float*)w; w += (size_t)N * 64 * 4;    // 12.8 MB
    float* a_s1 = (float*)w; w += (size_t)N * 4 * 4;
    float* a_d1 = (float*)w; w += (size_t)N * 4 * 4;
    float* a_s2 = (float*)w; w += (size_t)N * 4;
    float* a_d2 = (float*)w; w += (size_t)N * 4;
    int* cnt    = (int*)w;   w += (size_t)N * 4;         // reused as scan partial input
    int* partial= (int*)w;   w += (size_t)N * 4;
    int* rowptr = (int*)w;   w += (size_t)(N + 8) * 4;
    int* cursor = (int*)w;   w += (size_t)N * 4;
    int* bsum   = (int*)w;   w += 256 * 4;
    int* ssrc_s = (int*)w;   w += (size_t)Etot * 4;      // 6.6 MB

    const int TB = 256;
    const int nb = (N + 255) / 256;                      // 196 scan blocks (<=256)
    const int edgeBlocks = (E + TB - 1) / TB;
    const int etotBlocks = (Etot + TB - 1) / TB;
    const int nodeBlocks = (N + TB - 1) / TB;
    const int aggBlocks  = (N + 3) / 4;                  // 1 wave per node, 4/block

    // ---- CSR build (shared by both layers) ----
    init_cnt_k<<<nodeBlocks, TB, 0, stream>>>(cnt, N);
    hist_k<<<edgeBlocks, TB, 0, stream>>>(edst, E, cnt);
    scan1_k<<<nb, TB, 0, stream>>>(cnt, partial, bsum, N);
    scan2_k<<<1, TB, 0, stream>>>(bsum, nb);
    scan3_k<<<nb, TB, 0, stream>>>(partial, bsum, rowptr, cursor, N);
    cursor_k<<<nodeBlocks, TB, 0, stream>>>(rowptr, cursor, N);
    scatter_k<<<etotBlocks, TB, 0, stream>>>(esrc, edst, E, N, cursor, ssrc_s);

    // ---- layer 1 ----
    gemm_k<128><<<1024, TB, 0, stream>>>(x, W1, xw1, N);
    attn_scores_k<4, 32><<<(N * 4 + TB - 1) / TB, TB, 0, stream>>>(xw1, as1, ad1, a_s1, a_d1, N * 4);
    node_agg_k<4, 32, 1><<<aggBlocks, TB, 0, stream>>>(rowptr, ssrc_s, xw1, a_s1, a_d1,
                                                       b1, gamma, beta, mean, var, hbuf, N);

    // ---- layer 2 ----
    gemm_k<64><<<1024, TB, 0, stream>>>(hbuf, W2, xw2, N);
    attn_scores_k<1, 64><<<(N + TB - 1) / TB, TB, 0, stream>>>(xw2, as2, ad2, a_s2, a_d2, N);
    node_agg_k<1, 64, 2><<<aggBlocks, TB, 0, stream>>>(rowptr, ssrc_s, xw2, a_s2, a_d2,
                                                       b2, nullptr, nullptr, nullptr, nullptr,
                                                       out, N);
}

// Round 3
// 702.527 us; speedup vs baseline: 2.9226x; 1.1218x over previous
//
#include <hip/hip_runtime.h>
#include <hip/hip_bf16.h>

// ---------------------------------------------------------------------------
// GAT 2-layer pipeline. R3: xw tables stored bf16 (GEMM epilogue cast),
// bf16x2 gathers in aggregation, layer-2 agg packs 2 edges per wave.
// CSR (counting-sort by dst) + one wave per node fused online-softmax
// + aggregation + epilogue. No float atomics.
// ---------------------------------------------------------------------------

#define NNODES 50000

// Y[nrows,COLS] = X[nrows,128] @ W[128,COLS], stored as bf16.
template <int COLS>
__global__ __launch_bounds__(256) void gemm_k(const float* __restrict__ X,
                                              const float* __restrict__ W,
                                              __hip_bfloat16* __restrict__ Y, int nrows) {
    constexpr int K = 128;
    constexpr int CPT = 4;                    // cols per thread
    constexpr int ROWS = 256 * CPT / COLS;    // 8 (COLS=128) or 16 (COLS=64)
    constexpr int CG = COLS / CPT;            // col groups: 32 or 16
    __shared__ float sW[K * COLS];
    __shared__ float sX[ROWS][K];
    for (int i = threadIdx.x; i < K * COLS; i += 256) sW[i] = W[i];
    const int c0 = threadIdx.x % CG;
    const int r  = threadIdx.x / CG;
    for (int rb = blockIdx.x * ROWS; rb < nrows; rb += gridDim.x * ROWS) {
        __syncthreads();
        for (int i = threadIdx.x; i < ROWS * K; i += 256) {
            int rr = i / K, kk = i % K;
            int row = rb + rr;
            sX[rr][kk] = (row < nrows) ? X[(size_t)row * K + kk] : 0.0f;
        }
        __syncthreads();
        float acc[CPT] = {0.0f, 0.0f, 0.0f, 0.0f};
#pragma unroll 8
        for (int k = 0; k < K; ++k) {
            float xv = sX[r][k];
#pragma unroll
            for (int j = 0; j < CPT; ++j)
                acc[j] += xv * sW[k * COLS + c0 + j * CG];
        }
        int row = rb + r;
        if (row < nrows) {
#pragma unroll
            for (int j = 0; j < CPT; ++j)
                Y[(size_t)row * COLS + c0 + j * CG] = __float2bfloat16(acc[j]);
        }
    }
}

// a_src[n,h] = sum_c xw[n,h,c]*att_src[h,c]; one thread per (n,h); xw is bf16
template <int H, int C>
__global__ void attn_scores_k(const __hip_bfloat16* __restrict__ xw,
                              const float* __restrict__ atts,
                              const float* __restrict__ attd,
                              float* __restrict__ a_s, float* __restrict__ a_d,
                              int NH) {
    int i = blockIdx.x * blockDim.x + threadIdx.x;  // i = n*H + h
    if (i >= NH) return;
    const int h = i % H;
    const __hip_bfloat162* row2 = (const __hip_bfloat162*)(xw + (size_t)i * C);
    const float* ps = atts + h * C;
    const float* pd = attd + h * C;
    float as = 0.0f, ad = 0.0f;
#pragma unroll
    for (int c2 = 0; c2 < C / 2; ++c2) {
        float2 f = __bfloat1622float2(row2[c2]);
        as += f.x * ps[2 * c2] + f.y * ps[2 * c2 + 1];
        ad += f.x * pd[2 * c2] + f.y * pd[2 * c2 + 1];
    }
    a_s[i] = as;
    a_d[i] = ad;
}

// ----------------------------- CSR build -----------------------------------
__global__ void init_cnt_k(int* __restrict__ cnt, int Nn) {
    int i = blockIdx.x * blockDim.x + threadIdx.x;
    if (i < Nn) cnt[i] = 1;   // self-loop
}

__global__ void hist_k(const int* __restrict__ edst, int E, int* __restrict__ cnt) {
    int e = blockIdx.x * blockDim.x + threadIdx.x;
    if (e < E) atomicAdd(&cnt[edst[e]], 1);
}

__global__ __launch_bounds__(256) void scan1_k(const int* __restrict__ cnt,
                                               int* __restrict__ partial,
                                               int* __restrict__ bsum, int Nn) {
    __shared__ int sA[256];
    int i = blockIdx.x * 256 + threadIdx.x;
    sA[threadIdx.x] = (i < Nn) ? cnt[i] : 0;
    __syncthreads();
    for (int off = 1; off < 256; off <<= 1) {
        int u = (threadIdx.x >= off) ? sA[threadIdx.x - off] : 0;
        __syncthreads();
        sA[threadIdx.x] += u;
        __syncthreads();
    }
    if (i < Nn) partial[i] = sA[threadIdx.x];
    if (threadIdx.x == 255) bsum[blockIdx.x] = sA[255];
}

__global__ __launch_bounds__(256) void scan2_k(int* __restrict__ bsum, int nb) {
    __shared__ int sA[256];
    int t = threadIdx.x;
    sA[t] = (t < nb) ? bsum[t] : 0;
    __syncthreads();
    for (int off = 1; off < 256; off <<= 1) {
        int u = (t >= off) ? sA[t - off] : 0;
        __syncthreads();
        sA[t] += u;
        __syncthreads();
    }
    if (t < nb) bsum[t] = sA[t];
}

__global__ void scan3_k(const int* __restrict__ partial, const int* __restrict__ bsum,
                        int* __restrict__ rowptr, int Nn) {
    int i = blockIdx.x * 256 + threadIdx.x;
    if (i >= Nn) return;
    int b = blockIdx.x;
    int off = (b == 0) ? 0 : bsum[b - 1];
    rowptr[i + 1] = partial[i] + off;
    if (i == 0) rowptr[0] = 0;
}

__global__ void cursor_k(const int* __restrict__ rowptr, int* __restrict__ cursor, int Nn) {
    int i = blockIdx.x * blockDim.x + threadIdx.x;
    if (i < Nn) cursor[i] = rowptr[i];
}

__global__ void scatter_k(const int* __restrict__ esrc, const int* __restrict__ edst,
                          int E, int Nn, int* __restrict__ cursor,
                          int* __restrict__ ssrc_sorted) {
    int e = blockIdx.x * blockDim.x + threadIdx.x;
    int Etot = E + Nn;
    if (e >= Etot) return;
    int s, d;
    if (e < E) { s = esrc[e]; d = edst[e]; }
    else       { s = e - E;   d = e - E; }
    int pos = atomicAdd(&cursor[d], 1);
    ssrc_sorted[pos] = s;
}

// ---------------- layer 1: fused softmax + agg + bias/BN/ELU ---------------
// H=4, C=32, HC=128. One wave per node. Lane covers channels {2*lane, 2*lane+1}.
__global__ __launch_bounds__(256) void node_agg1_k(
    const int* __restrict__ rowptr, const int* __restrict__ ssrc,
    const __hip_bfloat16* __restrict__ xw,
    const float* __restrict__ a_s, const float* __restrict__ a_d,
    const float* __restrict__ bias,
    const float* __restrict__ gamma, const float* __restrict__ beta,
    const float* __restrict__ mean, const float* __restrict__ var,
    float* __restrict__ out, int Nn) {
    int n = (blockIdx.x * blockDim.x + threadIdx.x) >> 6;
    int lane = threadIdx.x & 63;
    if (n >= Nn) return;
    const int r0 = rowptr[n];
    const int deg = rowptr[n + 1] - r0;

    const float4 adn = ((const float4*)a_d)[n];
    const float ad0 = adn.x, ad1 = adn.y, ad2 = adn.z, ad3 = adn.w;

    // pass 1: lane-parallel online softmax (max & sum) per head
    float mx0 = -1e30f, mx1 = -1e30f, mx2 = -1e30f, mx3 = -1e30f;
    float sm0 = 0.f, sm1 = 0.f, sm2 = 0.f, sm3 = 0.f;
    for (int j = lane; j < deg; j += 64) {
        int s = ssrc[r0 + j];
        float4 as = ((const float4*)a_s)[s];
        float e0 = as.x + ad0; e0 = (e0 > 0.f) ? e0 : 0.2f * e0;
        float e1 = as.y + ad1; e1 = (e1 > 0.f) ? e1 : 0.2f * e1;
        float e2 = as.z + ad2; e2 = (e2 > 0.f) ? e2 : 0.2f * e2;
        float e3 = as.w + ad3; e3 = (e3 > 0.f) ? e3 : 0.2f * e3;
        float m;
        m = fmaxf(mx0, e0); sm0 = sm0 * __expf(mx0 - m) + __expf(e0 - m); mx0 = m;
        m = fmaxf(mx1, e1); sm1 = sm1 * __expf(mx1 - m) + __expf(e1 - m); mx1 = m;
        m = fmaxf(mx2, e2); sm2 = sm2 * __expf(mx2 - m) + __expf(e2 - m); mx2 = m;
        m = fmaxf(mx3, e3); sm3 = sm3 * __expf(mx3 - m) + __expf(e3 - m); mx3 = m;
    }
#pragma unroll
    for (int off = 32; off > 0; off >>= 1) {
        float m2, s2, m;
        m2 = __shfl_xor(mx0, off); s2 = __shfl_xor(sm0, off);
        m = fmaxf(mx0, m2); sm0 = sm0 * __expf(mx0 - m) + s2 * __expf(m2 - m); mx0 = m;
        m2 = __shfl_xor(mx1, off); s2 = __shfl_xor(sm1, off);
        m = fmaxf(mx1, m2); sm1 = sm1 * __expf(mx1 - m) + s2 * __expf(m2 - m); mx1 = m;
        m2 = __shfl_xor(mx2, off); s2 = __shfl_xor(sm2, off);
        m = fmaxf(mx2, m2); sm2 = sm2 * __expf(mx2 - m) + s2 * __expf(m2 - m); mx2 = m;
        m2 = __shfl_xor(mx3, off); s2 = __shfl_xor(sm3, off);
        m = fmaxf(mx3, m2); sm3 = sm3 * __expf(mx3 - m) + s2 * __expf(m2 - m); mx3 = m;
    }

    // this lane's head (channels 2*lane, 2*lane+1 are both in head lane>>4)
    const int h = lane >> 4;
    float mh = mx0, sh = sm0, adh = ad0;
    mh = (h == 1) ? mx1 : mh; sh = (h == 1) ? sm1 : sh; adh = (h == 1) ? ad1 : adh;
    mh = (h == 2) ? mx2 : mh; sh = (h == 2) ? sm2 : sh; adh = (h == 2) ? ad2 : adh;
    mh = (h == 3) ? mx3 : mh; sh = (h == 3) ? sm3 : sh; adh = (h == 3) ? ad3 : adh;
    const float inv = 1.0f / (sh + 1e-16f);

    // pass 2: sequential over edges, lanes parallel over channel pairs
    float accx = 0.f, accy = 0.f;
    const __hip_bfloat162* xw2p = (const __hip_bfloat162*)xw;
    for (int j = 0; j < deg; ++j) {
        int s = ssrc[r0 + j];
        float e = a_s[s * 4 + h] + adh;
        e = (e > 0.f) ? e : 0.2f * e;
        float alpha = __expf(e - mh) * inv;
        float2 f = __bfloat1622float2(xw2p[(size_t)s * 64 + lane]);
        accx += alpha * f.x;
        accy += alpha * f.y;
    }

    // epilogue: bias + BN + ELU, one float2 store per lane
    const int c = 2 * lane;
    float v0 = accx + bias[c];
    float v1 = accy + bias[c + 1];
    v0 = (v0 - mean[c])     * rsqrtf(var[c]     + 1e-5f) * gamma[c]     + beta[c];
    v1 = (v1 - mean[c + 1]) * rsqrtf(var[c + 1] + 1e-5f) * gamma[c + 1] + beta[c + 1];
    v0 = (v0 > 0.f) ? v0 : (__expf(v0) - 1.0f);
    v1 = (v1 > 0.f) ? v1 : (__expf(v1) - 1.0f);
    float2* op = (float2*)(out + (size_t)n * 128 + c);
    *op = make_float2(v0, v1);
}

// ---------------- layer 2: fused softmax + agg + bias ----------------------
// H=1, C=64. One wave per node; 2 edges per pass-2 iteration
// (lanes 0-31 edge j, lanes 32-63 edge j+1), each lane a bf16x2 channel pair.
__global__ __launch_bounds__(256) void node_agg2_k(
    const int* __restrict__ rowptr, const int* __restrict__ ssrc,
    const __hip_bfloat16* __restrict__ xw,
    const float* __restrict__ a_s, const float* __restrict__ a_d,
    const float* __restrict__ bias,
    float* __restrict__ out, int Nn) {
    int n = (blockIdx.x * blockDim.x + threadIdx.x) >> 6;
    int lane = threadIdx.x & 63;
    if (n >= Nn) return;
    const int r0 = rowptr[n];
    const int deg = rowptr[n + 1] - r0;
    const float adn = a_d[n];

    // pass 1: online softmax over edges
    float mx = -1e30f, sm = 0.f;
    for (int j = lane; j < deg; j += 64) {
        int s = ssrc[r0 + j];
        float e = a_s[s] + adn;
        e = (e > 0.f) ? e : 0.2f * e;
        float m = fmaxf(mx, e);
        sm = sm * __expf(mx - m) + __expf(e - m);
        mx = m;
    }
#pragma unroll
    for (int off = 32; off > 0; off >>= 1) {
        float m2 = __shfl_xor(mx, off);
        float s2 = __shfl_xor(sm, off);
        float m = fmaxf(mx, m2);
        sm = sm * __expf(mx - m) + s2 * __expf(m2 - m);
        mx = m;
    }
    const float inv = 1.0f / (sm + 1e-16f);

    // pass 2: two edges per iteration
    const int half = lane >> 5, li = lane & 31;
    float accx = 0.f, accy = 0.f;
    const __hip_bfloat162* xw2p = (const __hip_bfloat162*)xw;
    for (int j = 0; j < deg; j += 2) {
        int jj = j + half;
        bool ok = jj < deg;
        int s = ssrc[r0 + (ok ? jj : j)];
        float e = a_s[s] + adn;
        e = (e > 0.f) ? e : 0.2f * e;
        float alpha = ok ? __expf(e - mx) * inv : 0.0f;
        float2 f = __bfloat1622float2(xw2p[(size_t)s * 32 + li]);
        accx += alpha * f.x;
        accy += alpha * f.y;
    }
    accx += __shfl_down(accx, 32);
    accy += __shfl_down(accy, 32);
    if (lane < 32) {
        const int c = 2 * li;
        float2* op = (float2*)(out + (size_t)n * 64 + c);
        *op = make_float2(accx + bias[c], accy + bias[c + 1]);
    }
}

extern "C" void kernel_launch(void* const* d_in, const int* in_sizes, int n_in,
                              void* d_out, int out_size, void* d_ws, size_t ws_size,
                              hipStream_t stream) {
    const float* x     = (const float*)d_in[0];
    const int*   ei    = (const int*)d_in[1];
    const float* W1    = (const float*)d_in[2];
    const float* as1   = (const float*)d_in[3];
    const float* ad1   = (const float*)d_in[4];
    const float* b1    = (const float*)d_in[5];
    const float* gamma = (const float*)d_in[6];
    const float* beta  = (const float*)d_in[7];
    const float* mean  = (const float*)d_in[8];
    const float* var   = (const float*)d_in[9];
    const float* W2    = (const float*)d_in[10];
    const float* as2   = (const float*)d_in[11];
    const float* ad2   = (const float*)d_in[12];
    const float* b2    = (const float*)d_in[13];
    float* out = (float*)d_out;

    const int N = NNODES;
    const int E = in_sizes[1] / 2;
    const int Etot = E + N;
    const int* esrc = ei;
    const int* edst = ei + E;

    // workspace layout (all offsets 16-B aligned)
    char* w = (char*)d_ws;
    __hip_bfloat16* xw1 = (__hip_bfloat16*)w; w += (size_t)N * 128 * 2;  // 12.8 MB
    float* hbuf = (float*)w; w += (size_t)N * 128 * 4;                   // 25.6 MB
    __hip_bfloat16* xw2 = (__hip_bfloat16*)w; w += (size_t)N * 64 * 2;   // 6.4 MB
    float* a_s1 = (float*)w; w += (size_t)N * 4 * 4;
    float* a_d1 = (float*)w; w += (size_t)N * 4 * 4;
    float* a_s2 = (float*)w; w += (size_t)N * 4;
    float* a_d2 = (float*)w; w += (size_t)N * 4;
    int* cnt    = (int*)w;   w += (size_t)N * 4;
    int* partial= (int*)w;   w += (size_t)N * 4;
    int* rowptr = (int*)w;   w += (size_t)(N + 8) * 4;
    int* cursor = (int*)w;   w += (size_t)N * 4;
    int* bsum   = (int*)w;   w += 256 * 4;
    int* ssrc_s = (int*)w;   w += (size_t)Etot * 4;                      // 6.6 MB

    const int TB = 256;
    const int nb = (N + 255) / 256;
    const int edgeBlocks = (E + TB - 1) / TB;
    const int etotBlocks = (Etot + TB - 1) / TB;
    const int nodeBlocks = (N + TB - 1) / TB;
    const int aggBlocks  = (N + 3) / 4;   // one wave per node, 4 waves/block

    // ---- CSR build (shared by both layers) ----
    init_cnt_k<<<nodeBlocks, TB, 0, stream>>>(cnt, N);
    hist_k<<<edgeBlocks, TB, 0, stream>>>(edst, E, cnt);
    scan1_k<<<nb, TB, 0, stream>>>(cnt, partial, bsum, N);
    scan2_k<<<1, TB, 0, stream>>>(bsum, nb);
    scan3_k<<<nb, TB, 0, stream>>>(partial, bsum, rowptr, N);
    cursor_k<<<nodeBlocks, TB, 0, stream>>>(rowptr, cursor, N);
    scatter_k<<<etotBlocks, TB, 0, stream>>>(esrc, edst, E, N, cursor, ssrc_s);

    // ---- layer 1 ----
    gemm_k<128><<<1024, TB, 0, stream>>>(x, W1, xw1, N);
    attn_scores_k<4, 32><<<(N * 4 + TB - 1) / TB, TB, 0, stream>>>(xw1, as1, ad1, a_s1, a_d1, N * 4);
    node_agg1_k<<<aggBlocks, TB, 0, stream>>>(rowptr, ssrc_s, xw1, a_s1, a_d1,
                                              b1, gamma, beta, mean, var, hbuf, N);

    // ---- layer 2 ----
    gemm_k<64><<<1024, TB, 0, stream>>>(hbuf, W2, xw2, N);
    attn_scores_k<1, 64><<<(N + TB - 1) / TB, TB, 0, stream>>>(xw2, as2, ad2, a_s2, a_d2, N);
    node_agg2_k<<<aggBlocks, TB, 0, stream>>>(rowptr, ssrc_s, xw2, a_s2, a_d2, b2, out, N);
}

// Round 4
// 540.420 us; speedup vs baseline: 3.7993x; 1.3000x over previous
//
#include <hip/hip_runtime.h>
#include <hip/hip_bf16.h>
#include <hip/hip_fp16.h>

// ---------------------------------------------------------------------------
// GAT 2-layer pipeline. R4: MFMA bf16 GEMMs (W repacked to fragment layout),
// edge-parallel fp16 alpha precompute, lean gather-only aggregation.
// CSR (counting-sort by dst). No float atomics.
// ---------------------------------------------------------------------------

#define NNODES 50000

typedef __bf16 bf16x8 __attribute__((ext_vector_type(8)));
typedef float f32x4 __attribute__((ext_vector_type(4)));

// ------------------------- W repack to MFMA B-fragment ----------------------
// Wp[((t*4+s)*64+lane)*8+j] = bf16(W[(s*32+(lane>>4)*8+j)*COLS + t*16+(lane&15)])
template <int COLS>
__global__ void wpack_k(const float* __restrict__ W, __hip_bfloat16* __restrict__ Wp) {
    constexpr int TOT = (COLS / 16) * 4 * 64;
    int i = blockIdx.x * blockDim.x + threadIdx.x;
    if (i >= TOT) return;
    int l = i & 63, s = (i >> 6) & 3, t = i >> 8;
    int quad = l >> 4, col = l & 15;
#pragma unroll
    for (int j = 0; j < 8; ++j) {
        float f = W[(s * 32 + quad * 8 + j) * COLS + t * 16 + col];
        Wp[(size_t)i * 8 + j] = __float2bfloat16(f);
    }
}

// ------------------------- MFMA GEMM: Y = X @ W -----------------------------
// M rows (mult of 16), K=128, COLS in {128,64}. 4 waves/block, 16 rows/wave.
template <int COLS, bool IN_BF16>
__global__ __launch_bounds__(256) void gemm_mfma_k(const void* __restrict__ Xv,
                                                   const __hip_bfloat16* __restrict__ Wp,
                                                   __hip_bfloat16* __restrict__ Y, int M) {
    const int wid = threadIdx.x >> 6, lane = threadIdx.x & 63;
    const int tile = blockIdx.x * 4 + wid;
    if (tile * 16 >= M) return;
    const int quad = lane >> 4, col = lane & 15;
    const int row = tile * 16 + col;

    bf16x8 afr[4];
    if (IN_BF16) {
        const __hip_bfloat16* X = (const __hip_bfloat16*)Xv;
#pragma unroll
        for (int s = 0; s < 4; ++s)
            afr[s] = *(const bf16x8*)(X + (size_t)row * 128 + s * 32 + quad * 8);
    } else {
        const float* X = (const float*)Xv;
#pragma unroll
        for (int s = 0; s < 4; ++s) {
            const float4* p = (const float4*)(X + (size_t)row * 128 + s * 32 + quad * 8);
            float4 f0 = p[0], f1 = p[1];
            afr[s][0] = (__bf16)f0.x; afr[s][1] = (__bf16)f0.y;
            afr[s][2] = (__bf16)f0.z; afr[s][3] = (__bf16)f0.w;
            afr[s][4] = (__bf16)f1.x; afr[s][5] = (__bf16)f1.y;
            afr[s][6] = (__bf16)f1.z; afr[s][7] = (__bf16)f1.w;
        }
    }

    const bf16x8* Wp8 = (const bf16x8*)Wp;
#pragma unroll
    for (int t = 0; t < COLS / 16; ++t) {
        f32x4 acc = {0.f, 0.f, 0.f, 0.f};
#pragma unroll
        for (int s = 0; s < 4; ++s) {
            bf16x8 bfr = Wp8[(t * 4 + s) * 64 + lane];
            acc = __builtin_amdgcn_mfma_f32_16x16x32_bf16(afr[s], bfr, acc, 0, 0, 0);
        }
#pragma unroll
        for (int r = 0; r < 4; ++r)
            Y[(size_t)(tile * 16 + quad * 4 + r) * COLS + t * 16 + col] =
                __float2bfloat16(acc[r]);
    }
}

// a_src[n,h] = sum_c xw[n,h,c]*att_src[h,c]; one thread per (n,h); xw is bf16
template <int H, int C>
__global__ void attn_scores_k(const __hip_bfloat16* __restrict__ xw,
                              const float* __restrict__ atts,
                              const float* __restrict__ attd,
                              float* __restrict__ a_s, float* __restrict__ a_d,
                              int NH) {
    int i = blockIdx.x * blockDim.x + threadIdx.x;  // i = n*H + h
    if (i >= NH) return;
    const int h = i % H;
    const __hip_bfloat162* row2 = (const __hip_bfloat162*)(xw + (size_t)i * C);
    const float* ps = atts + h * C;
    const float* pd = attd + h * C;
    float as = 0.0f, ad = 0.0f;
#pragma unroll
    for (int c2 = 0; c2 < C / 2; ++c2) {
        float2 f = __bfloat1622float2(row2[c2]);
        as += f.x * ps[2 * c2] + f.y * ps[2 * c2 + 1];
        ad += f.x * pd[2 * c2] + f.y * pd[2 * c2 + 1];
    }
    a_s[i] = as;
    a_d[i] = ad;
}

// ----------------------------- CSR build -----------------------------------
__global__ void init_cnt_k(int* __restrict__ cnt, int Nn) {
    int i = blockIdx.x * blockDim.x + threadIdx.x;
    if (i < Nn) cnt[i] = 1;   // self-loop
}

__global__ void hist_k(const int* __restrict__ edst, int E, int* __restrict__ cnt) {
    int e = blockIdx.x * blockDim.x + threadIdx.x;
    if (e < E) atomicAdd(&cnt[edst[e]], 1);
}

__global__ __launch_bounds__(256) void scan1_k(const int* __restrict__ cnt,
                                               int* __restrict__ partial,
                                               int* __restrict__ bsum, int Nn) {
    __shared__ int sA[256];
    int i = blockIdx.x * 256 + threadIdx.x;
    sA[threadIdx.x] = (i < Nn) ? cnt[i] : 0;
    __syncthreads();
    for (int off = 1; off < 256; off <<= 1) {
        int u = (threadIdx.x >= off) ? sA[threadIdx.x - off] : 0;
        __syncthreads();
        sA[threadIdx.x] += u;
        __syncthreads();
    }
    if (i < Nn) partial[i] = sA[threadIdx.x];
    if (threadIdx.x == 255) bsum[blockIdx.x] = sA[255];
}

__global__ __launch_bounds__(256) void scan2_k(int* __restrict__ bsum, int nb) {
    __shared__ int sA[256];
    int t = threadIdx.x;
    sA[t] = (t < nb) ? bsum[t] : 0;
    __syncthreads();
    for (int off = 1; off < 256; off <<= 1) {
        int u = (t >= off) ? sA[t - off] : 0;
        __syncthreads();
        sA[t] += u;
        __syncthreads();
    }
    if (t < nb) bsum[t] = sA[t];
}

__global__ void scan3_k(const int* __restrict__ partial, const int* __restrict__ bsum,
                        int* __restrict__ rowptr, int Nn) {
    int i = blockIdx.x * 256 + threadIdx.x;
    if (i >= Nn) return;
    int b = blockIdx.x;
    int off = (b == 0) ? 0 : bsum[b - 1];
    rowptr[i + 1] = partial[i] + off;
    if (i == 0) rowptr[0] = 0;
}

__global__ void cursor_k(const int* __restrict__ rowptr, int* __restrict__ cursor, int Nn) {
    int i = blockIdx.x * blockDim.x + threadIdx.x;
    if (i < Nn) cursor[i] = rowptr[i];
}

__global__ void scatter_k(const int* __restrict__ esrc, const int* __restrict__ edst,
                          int E, int Nn, int* __restrict__ cursor,
                          int* __restrict__ ssrc_sorted, int* __restrict__ dst_sorted) {
    int e = blockIdx.x * blockDim.x + threadIdx.x;
    int Etot = E + Nn;
    if (e >= Etot) return;
    int s, d;
    if (e < E) { s = esrc[e]; d = edst[e]; }
    else       { s = e - E;   d = e - E; }
    int pos = atomicAdd(&cursor[d], 1);
    ssrc_sorted[pos] = s;
    dst_sorted[pos] = d;
}

// ---------------- softmax stats: one wave per node, H=4 --------------------
__global__ __launch_bounds__(256) void stats1_k(
    const int* __restrict__ rowptr, const int* __restrict__ ssrc,
    const float* __restrict__ a_s, const float* __restrict__ a_d,
    float4* __restrict__ mo, float4* __restrict__ invo, int Nn) {
    int n = (blockIdx.x * blockDim.x + threadIdx.x) >> 6;
    int lane = threadIdx.x & 63;
    if (n >= Nn) return;
    const int r0 = rowptr[n];
    const int deg = rowptr[n + 1] - r0;
    const float4 adn = ((const float4*)a_d)[n];

    float mx0 = -1e30f, mx1 = -1e30f, mx2 = -1e30f, mx3 = -1e30f;
    float sm0 = 0.f, sm1 = 0.f, sm2 = 0.f, sm3 = 0.f;
    for (int j = lane; j < deg; j += 64) {
        int s = ssrc[r0 + j];
        float4 as = ((const float4*)a_s)[s];
        float e0 = as.x + adn.x; e0 = (e0 > 0.f) ? e0 : 0.2f * e0;
        float e1 = as.y + adn.y; e1 = (e1 > 0.f) ? e1 : 0.2f * e1;
        float e2 = as.z + adn.z; e2 = (e2 > 0.f) ? e2 : 0.2f * e2;
        float e3 = as.w + adn.w; e3 = (e3 > 0.f) ? e3 : 0.2f * e3;
        float m;
        m = fmaxf(mx0, e0); sm0 = sm0 * __expf(mx0 - m) + __expf(e0 - m); mx0 = m;
        m = fmaxf(mx1, e1); sm1 = sm1 * __expf(mx1 - m) + __expf(e1 - m); mx1 = m;
        m = fmaxf(mx2, e2); sm2 = sm2 * __expf(mx2 - m) + __expf(e2 - m); mx2 = m;
        m = fmaxf(mx3, e3); sm3 = sm3 * __expf(mx3 - m) + __expf(e3 - m); mx3 = m;
    }
#pragma unroll
    for (int off = 32; off > 0; off >>= 1) {
        float m2, s2, m;
        m2 = __shfl_xor(mx0, off); s2 = __shfl_xor(sm0, off);
        m = fmaxf(mx0, m2); sm0 = sm0 * __expf(mx0 - m) + s2 * __expf(m2 - m); mx0 = m;
        m2 = __shfl_xor(mx1, off); s2 = __shfl_xor(sm1, off);
        m = fmaxf(mx1, m2); sm1 = sm1 * __expf(mx1 - m) + s2 * __expf(m2 - m); mx1 = m;
        m2 = __shfl_xor(mx2, off); s2 = __shfl_xor(sm2, off);
        m = fmaxf(mx2, m2); sm2 = sm2 * __expf(mx2 - m) + s2 * __expf(m2 - m); mx2 = m;
        m2 = __shfl_xor(mx3, off); s2 = __shfl_xor(sm3, off);
        m = fmaxf(mx3, m2); sm3 = sm3 * __expf(mx3 - m) + s2 * __expf(m2 - m); mx3 = m;
    }
    if (lane == 0) {
        mo[n]   = make_float4(mx0, mx1, mx2, mx3);
        invo[n] = make_float4(1.f / (sm0 + 1e-16f), 1.f / (sm1 + 1e-16f),
                              1.f / (sm2 + 1e-16f), 1.f / (sm3 + 1e-16f));
    }
}

// H=1 stats
__global__ __launch_bounds__(256) void stats2_k(
    const int* __restrict__ rowptr, const int* __restrict__ ssrc,
    const float* __restrict__ a_s, const float* __restrict__ a_d,
    float* __restrict__ mo, float* __restrict__ invo, int Nn) {
    int n = (blockIdx.x * blockDim.x + threadIdx.x) >> 6;
    int lane = threadIdx.x & 63;
    if (n >= Nn) return;
    const int r0 = rowptr[n];
    const int deg = rowptr[n + 1] - r0;
    const float adn = a_d[n];
    float mx = -1e30f, sm = 0.f;
    for (int j = lane; j < deg; j += 64) {
        int s = ssrc[r0 + j];
        float e = a_s[s] + adn;
        e = (e > 0.f) ? e : 0.2f * e;
        float m = fmaxf(mx, e);
        sm = sm * __expf(mx - m) + __expf(e - m);
        mx = m;
    }
#pragma unroll
    for (int off = 32; off > 0; off >>= 1) {
        float m2 = __shfl_xor(mx, off);
        float s2 = __shfl_xor(sm, off);
        float m = fmaxf(mx, m2);
        sm = sm * __expf(mx - m) + s2 * __expf(m2 - m);
        mx = m;
    }
    if (lane == 0) { mo[n] = mx; invo[n] = 1.f / (sm + 1e-16f); }
}

// ---------------- edge-parallel alpha (fp16) -------------------------------
__global__ void alpha1_k(const int* __restrict__ ssrc, const int* __restrict__ dsts,
                         const float* __restrict__ a_s, const float* __restrict__ a_d,
                         const float4* __restrict__ mo, const float4* __restrict__ invo,
                         __half2* __restrict__ alph, int Etot) {
    int e = blockIdx.x * blockDim.x + threadIdx.x;
    if (e >= Etot) return;
    int s = ssrc[e], d = dsts[e];
    float4 as = ((const float4*)a_s)[s];
    float4 ad = ((const float4*)a_d)[d];
    float4 m = mo[d], iv = invo[d];
    float e0 = as.x + ad.x; e0 = (e0 > 0.f) ? e0 : 0.2f * e0;
    float e1 = as.y + ad.y; e1 = (e1 > 0.f) ? e1 : 0.2f * e1;
    float e2 = as.z + ad.z; e2 = (e2 > 0.f) ? e2 : 0.2f * e2;
    float e3 = as.w + ad.w; e3 = (e3 > 0.f) ? e3 : 0.2f * e3;
    float a0 = __expf(e0 - m.x) * iv.x;
    float a1 = __expf(e1 - m.y) * iv.y;
    float a2 = __expf(e2 - m.z) * iv.z;
    float a3 = __expf(e3 - m.w) * iv.w;
    alph[(size_t)e * 2]     = __floats2half2_rn(a0, a1);
    alph[(size_t)e * 2 + 1] = __floats2half2_rn(a2, a3);
}

__global__ void alpha2_k(const int* __restrict__ ssrc, const int* __restrict__ dsts,
                         const float* __restrict__ a_s, const float* __restrict__ a_d,
                         const float* __restrict__ mo, const float* __restrict__ invo,
                         __half* __restrict__ alph, int Etot) {
    int e = blockIdx.x * blockDim.x + threadIdx.x;
    if (e >= Etot) return;
    int s = ssrc[e], d = dsts[e];
    float v = a_s[s] + a_d[d];
    v = (v > 0.f) ? v : 0.2f * v;
    alph[e] = __float2half(__expf(v - mo[d]) * invo[d]);
}

// ---------------- layer 1 aggregation: gather + FMA only -------------------
// H=4, C=32, HC=128. One wave/node; lane covers channels {2*lane, 2*lane+1}.
__global__ __launch_bounds__(256) void node_agg1_k(
    const int* __restrict__ rowptr, const int* __restrict__ ssrc,
    const __hip_bfloat16* __restrict__ xw, const __half* __restrict__ alph,
    const float* __restrict__ bias,
    const float* __restrict__ gamma, const float* __restrict__ beta,
    const float* __restrict__ mean, const float* __restrict__ var,
    __hip_bfloat16* __restrict__ out, int Nn) {
    int n = (blockIdx.x * blockDim.x + threadIdx.x) >> 6;
    int lane = threadIdx.x & 63;
    if (n >= Nn) return;
    const int r0 = rowptr[n];
    const int deg = rowptr[n + 1] - r0;
    const int h = lane >> 4;
    const __half* al = alph + (size_t)r0 * 4 + h;
    const int* sp = ssrc + r0;
    const __hip_bfloat162* xw2p = (const __hip_bfloat162*)xw;

    float accx = 0.f, accy = 0.f;
#pragma unroll 4
    for (int j = 0; j < deg; ++j) {
        int s = sp[j];
        float a = __half2float(al[(size_t)j * 4]);
        float2 f = __bfloat1622float2(xw2p[(size_t)s * 64 + lane]);
        accx += a * f.x;
        accy += a * f.y;
    }

    const int c = 2 * lane;
    float v0 = accx + bias[c];
    float v1 = accy + bias[c + 1];
    v0 = (v0 - mean[c])     * rsqrtf(var[c]     + 1e-5f) * gamma[c]     + beta[c];
    v1 = (v1 - mean[c + 1]) * rsqrtf(var[c + 1] + 1e-5f) * gamma[c + 1] + beta[c + 1];
    v0 = (v0 > 0.f) ? v0 : (__expf(v0) - 1.0f);
    v1 = (v1 > 0.f) ? v1 : (__expf(v1) - 1.0f);
    __hip_bfloat162* op = (__hip_bfloat162*)(out + (size_t)n * 128 + c);
    *op = __hip_bfloat162(__float2bfloat16(v0), __float2bfloat16(v1));
}

// ---------------- layer 2 aggregation --------------------------------------
// H=1, C=64. One wave/node; 2 edges/iter (half-waves), lane = channel pair.
__global__ __launch_bounds__(256) void node_agg2_k(
    const int* __restrict__ rowptr, const int* __restrict__ ssrc,
    const __hip_bfloat16* __restrict__ xw, const __half* __restrict__ alph,
    const float* __restrict__ bias, float* __restrict__ out, int Nn) {
    int n = (blockIdx.x * blockDim.x + threadIdx.x) >> 6;
    int lane = threadIdx.x & 63;
    if (n >= Nn) return;
    const int r0 = rowptr[n];
    const int deg = rowptr[n + 1] - r0;
    const int half = lane >> 5, li = lane & 31;
    const __hip_bfloat162* xw2p = (const __hip_bfloat162*)xw;

    float accx = 0.f, accy = 0.f;
#pragma unroll 2
    for (int j = 0; j < deg; j += 2) {
        int jj = j + half;
        bool ok = jj < deg;
        int s = ssrc[r0 + (ok ? jj : j)];
        float a = ok ? __half2float(alph[r0 + jj]) : 0.0f;
        float2 f = __bfloat1622float2(xw2p[(size_t)s * 32 + li]);
        accx += a * f.x;
        accy += a * f.y;
    }
    accx += __shfl_down(accx, 32);
    accy += __shfl_down(accy, 32);
    if (lane < 32) {
        const int c = 2 * li;
        float2* op = (float2*)(out + (size_t)n * 64 + c);
        *op = make_float2(accx + bias[c], accy + bias[c + 1]);
    }
}

extern "C" void kernel_launch(void* const* d_in, const int* in_sizes, int n_in,
                              void* d_out, int out_size, void* d_ws, size_t ws_size,
                              hipStream_t stream) {
    const float* x     = (const float*)d_in[0];
    const int*   ei    = (const int*)d_in[1];
    const float* W1    = (const float*)d_in[2];
    const float* as1   = (const float*)d_in[3];
    const float* ad1   = (const float*)d_in[4];
    const float* b1    = (const float*)d_in[5];
    const float* gamma = (const float*)d_in[6];
    const float* beta  = (const float*)d_in[7];
    const float* mean  = (const float*)d_in[8];
    const float* var   = (const float*)d_in[9];
    const float* W2    = (const float*)d_in[10];
    const float* as2   = (const float*)d_in[11];
    const float* ad2   = (const float*)d_in[12];
    const float* b2    = (const float*)d_in[13];
    float* out = (float*)d_out;

    const int N = NNODES;
    const int E = in_sizes[1] / 2;
    const int Etot = E + N;
    const int* esrc = ei;
    const int* edst = ei + E;

    // workspace layout (16-B aligned segments), ~62 MB total
    char* w = (char*)d_ws;
    __hip_bfloat16* xw1 = (__hip_bfloat16*)w; w += (size_t)N * 128 * 2;   // 12.8 MB
    __hip_bfloat16* hbuf = (__hip_bfloat16*)w; w += (size_t)N * 128 * 2;  // 12.8 MB
    __hip_bfloat16* xw2 = (__hip_bfloat16*)w; w += (size_t)N * 64 * 2;    // 6.4 MB
    float* a_s1 = (float*)w; w += (size_t)N * 4 * 4;   // also a_s2 (reuse)
    float* a_d1 = (float*)w; w += (size_t)N * 4 * 4;   // also a_d2 (reuse)
    float* m1   = (float*)w; w += (size_t)N * 4 * 4;   // also m2
    float* inv1 = (float*)w; w += (size_t)N * 4 * 4;   // also inv2
    __half* alpha1 = (__half*)w; w += (size_t)Etot * 4 * 2 + 16;  // 13.2 MB; also alpha2
    int* cnt    = (int*)w;   w += (size_t)N * 4;       // reused as cursor
    int* partial= (int*)w;   w += (size_t)N * 4;
    int* rowptr = (int*)w;   w += (size_t)(N + 8) * 4;
    int* bsum   = (int*)w;   w += 1024;
    int* ssrc_s = (int*)w;   w += (size_t)Etot * 4 + 16;   // 6.6 MB
    int* dst_s  = (int*)w;   w += (size_t)Etot * 4 + 16;   // 6.6 MB
    __hip_bfloat16* wp1 = (__hip_bfloat16*)w; w += 8 * 4 * 64 * 8 * 2;  // 32 KB
    __hip_bfloat16* wp2 = (__hip_bfloat16*)w; w += 4 * 4 * 64 * 8 * 2;  // 16 KB
    float* a_s2 = a_s1; float* a_d2 = a_d1;
    float* m2 = m1; float* inv2 = inv1;
    __half* alpha2 = alpha1;

    const int TB = 256;
    const int nb = (N + 255) / 256;
    const int edgeBlocks = (E + TB - 1) / TB;
    const int etotBlocks = (Etot + TB - 1) / TB;
    const int nodeBlocks = (N + TB - 1) / TB;
    const int aggBlocks  = (N + 3) / 4;            // one wave/node, 4 waves/block
    const int gemmBlocks = (N / 16 + 3) / 4;       // 3125 row-tiles / 4 waves

    // ---- W repack (independent) ----
    wpack_k<128><<<(8 * 4 * 64 + TB - 1) / TB, TB, 0, stream>>>(W1, wp1);
    wpack_k<64><<<(4 * 4 * 64 + TB - 1) / TB, TB, 0, stream>>>(W2, wp2);

    // ---- CSR build (shared by both layers) ----
    init_cnt_k<<<nodeBlocks, TB, 0, stream>>>(cnt, N);
    hist_k<<<edgeBlocks, TB, 0, stream>>>(edst, E, cnt);
    scan1_k<<<nb, TB, 0, stream>>>(cnt, partial, bsum, N);
    scan2_k<<<1, TB, 0, stream>>>(bsum, nb);
    scan3_k<<<nb, TB, 0, stream>>>(partial, bsum, rowptr, N);
    cursor_k<<<nodeBlocks, TB, 0, stream>>>(rowptr, cnt, N);
    scatter_k<<<etotBlocks, TB, 0, stream>>>(esrc, edst, E, N, cnt, ssrc_s, dst_s);

    // ---- layer 1 ----
    gemm_mfma_k<128, false><<<gemmBlocks, TB, 0, stream>>>(x, wp1, xw1, N);
    attn_scores_k<4, 32><<<(N * 4 + TB - 1) / TB, TB, 0, stream>>>(xw1, as1, ad1, a_s1, a_d1, N * 4);
    stats1_k<<<aggBlocks, TB, 0, stream>>>(rowptr, ssrc_s, a_s1, a_d1,
                                           (float4*)m1, (float4*)inv1, N);
    alpha1_k<<<etotBlocks, TB, 0, stream>>>(ssrc_s, dst_s, a_s1, a_d1,
                                            (const float4*)m1, (const float4*)inv1,
                                            (__half2*)alpha1, Etot);
    node_agg1_k<<<aggBlocks, TB, 0, stream>>>(rowptr, ssrc_s, xw1, alpha1,
                                              b1, gamma, beta, mean, var, hbuf, N);

    // ---- layer 2 ----
    gemm_mfma_k<64, true><<<gemmBlocks, TB, 0, stream>>>(hbuf, wp2, xw2, N);
    attn_scores_k<1, 64><<<(N + TB - 1) / TB, TB, 0, stream>>>(xw2, as2, ad2, a_s2, a_d2, N);
    stats2_k<<<aggBlocks, TB, 0, stream>>>(rowptr, ssrc_s, a_s2, a_d2, m2, inv2, N);
    alpha2_k<<<etotBlocks, TB, 0, stream>>>(ssrc_s, dst_s, a_s2, a_d2, m2, inv2, alpha2, Etot);
    node_agg2_k<<<aggBlocks, TB, 0, stream>>>(rowptr, ssrc_s, xw2, alpha2, b2, out, N);
}

// Round 5
// 528.321 us; speedup vs baseline: 3.8863x; 1.0229x over previous
//
#include <hip/hip_runtime.h>
#include <hip/hip_bf16.h>
#include <hip/hip_fp16.h>

// ---------------------------------------------------------------------------
// GAT 2-layer pipeline. R5: alpha fused into stats kernels (coalesced writes,
// dst array eliminated), scatter writes only ssrc (halved write-allocate
// traffic). MFMA bf16 GEMMs, CSR counting sort, no float atomics.
// ---------------------------------------------------------------------------

#define NNODES 50000

typedef __bf16 bf16x8 __attribute__((ext_vector_type(8)));
typedef float f32x4 __attribute__((ext_vector_type(4)));

// ------------------------- W repack to MFMA B-fragment ----------------------
template <int COLS>
__global__ void wpack_k(const float* __restrict__ W, __hip_bfloat16* __restrict__ Wp) {
    constexpr int TOT = (COLS / 16) * 4 * 64;
    int i = blockIdx.x * blockDim.x + threadIdx.x;
    if (i >= TOT) return;
    int l = i & 63, s = (i >> 6) & 3, t = i >> 8;
    int quad = l >> 4, col = l & 15;
#pragma unroll
    for (int j = 0; j < 8; ++j) {
        float f = W[(s * 32 + quad * 8 + j) * COLS + t * 16 + col];
        Wp[(size_t)i * 8 + j] = __float2bfloat16(f);
    }
}

// ------------------------- MFMA GEMM: Y = X @ W -----------------------------
template <int COLS, bool IN_BF16>
__global__ __launch_bounds__(256) void gemm_mfma_k(const void* __restrict__ Xv,
                                                   const __hip_bfloat16* __restrict__ Wp,
                                                   __hip_bfloat16* __restrict__ Y, int M) {
    const int wid = threadIdx.x >> 6, lane = threadIdx.x & 63;
    const int tile = blockIdx.x * 4 + wid;
    if (tile * 16 >= M) return;
    const int quad = lane >> 4, col = lane & 15;
    const int row = tile * 16 + col;

    bf16x8 afr[4];
    if (IN_BF16) {
        const __hip_bfloat16* X = (const __hip_bfloat16*)Xv;
#pragma unroll
        for (int s = 0; s < 4; ++s)
            afr[s] = *(const bf16x8*)(X + (size_t)row * 128 + s * 32 + quad * 8);
    } else {
        const float* X = (const float*)Xv;
#pragma unroll
        for (int s = 0; s < 4; ++s) {
            const float4* p = (const float4*)(X + (size_t)row * 128 + s * 32 + quad * 8);
            float4 f0 = p[0], f1 = p[1];
            afr[s][0] = (__bf16)f0.x; afr[s][1] = (__bf16)f0.y;
            afr[s][2] = (__bf16)f0.z; afr[s][3] = (__bf16)f0.w;
            afr[s][4] = (__bf16)f1.x; afr[s][5] = (__bf16)f1.y;
            afr[s][6] = (__bf16)f1.z; afr[s][7] = (__bf16)f1.w;
        }
    }

    const bf16x8* Wp8 = (const bf16x8*)Wp;
#pragma unroll
    for (int t = 0; t < COLS / 16; ++t) {
        f32x4 acc = {0.f, 0.f, 0.f, 0.f};
#pragma unroll
        for (int s = 0; s < 4; ++s) {
            bf16x8 bfr = Wp8[(t * 4 + s) * 64 + lane];
            acc = __builtin_amdgcn_mfma_f32_16x16x32_bf16(afr[s], bfr, acc, 0, 0, 0);
        }
#pragma unroll
        for (int r = 0; r < 4; ++r)
            Y[(size_t)(tile * 16 + quad * 4 + r) * COLS + t * 16 + col] =
                __float2bfloat16(acc[r]);
    }
}

// a_src[n,h] = sum_c xw[n,h,c]*att_src[h,c]; one thread per (n,h); xw is bf16
template <int H, int C>
__global__ void attn_scores_k(const __hip_bfloat16* __restrict__ xw,
                              const float* __restrict__ atts,
                              const float* __restrict__ attd,
                              float* __restrict__ a_s, float* __restrict__ a_d,
                              int NH) {
    int i = blockIdx.x * blockDim.x + threadIdx.x;  // i = n*H + h
    if (i >= NH) return;
    const int h = i % H;
    const __hip_bfloat162* row2 = (const __hip_bfloat162*)(xw + (size_t)i * C);
    const float* ps = atts + h * C;
    const float* pd = attd + h * C;
    float as = 0.0f, ad = 0.0f;
#pragma unroll
    for (int c2 = 0; c2 < C / 2; ++c2) {
        float2 f = __bfloat1622float2(row2[c2]);
        as += f.x * ps[2 * c2] + f.y * ps[2 * c2 + 1];
        ad += f.x * pd[2 * c2] + f.y * pd[2 * c2 + 1];
    }
    a_s[i] = as;
    a_d[i] = ad;
}

// ----------------------------- CSR build -----------------------------------
__global__ void init_cnt_k(int* __restrict__ cnt, int Nn) {
    int i = blockIdx.x * blockDim.x + threadIdx.x;
    if (i < Nn) cnt[i] = 1;   // self-loop
}

__global__ void hist_k(const int* __restrict__ edst, int E, int* __restrict__ cnt) {
    int e = blockIdx.x * blockDim.x + threadIdx.x;
    if (e < E) atomicAdd(&cnt[edst[e]], 1);
}

__global__ __launch_bounds__(256) void scan1_k(const int* __restrict__ cnt,
                                               int* __restrict__ partial,
                                               int* __restrict__ bsum, int Nn) {
    __shared__ int sA[256];
    int i = blockIdx.x * 256 + threadIdx.x;
    sA[threadIdx.x] = (i < Nn) ? cnt[i] : 0;
    __syncthreads();
    for (int off = 1; off < 256; off <<= 1) {
        int u = (threadIdx.x >= off) ? sA[threadIdx.x - off] : 0;
        __syncthreads();
        sA[threadIdx.x] += u;
        __syncthreads();
    }
    if (i < Nn) partial[i] = sA[threadIdx.x];
    if (threadIdx.x == 255) bsum[blockIdx.x] = sA[255];
}

__global__ __launch_bounds__(256) void scan2_k(int* __restrict__ bsum, int nb) {
    __shared__ int sA[256];
    int t = threadIdx.x;
    sA[t] = (t < nb) ? bsum[t] : 0;
    __syncthreads();
    for (int off = 1; off < 256; off <<= 1) {
        int u = (t >= off) ? sA[t - off] : 0;
        __syncthreads();
        sA[t] += u;
        __syncthreads();
    }
    if (t < nb) bsum[t] = sA[t];
}

__global__ void scan3_k(const int* __restrict__ partial, const int* __restrict__ bsum,
                        int* __restrict__ rowptr, int Nn) {
    int i = blockIdx.x * 256 + threadIdx.x;
    if (i >= Nn) return;
    int b = blockIdx.x;
    int off = (b == 0) ? 0 : bsum[b - 1];
    rowptr[i + 1] = partial[i] + off;
    if (i == 0) rowptr[0] = 0;
}

__global__ void cursor_k(const int* __restrict__ rowptr, int* __restrict__ cursor, int Nn) {
    int i = blockIdx.x * blockDim.x + threadIdx.x;
    if (i < Nn) cursor[i] = rowptr[i];
}

__global__ void scatter_k(const int* __restrict__ esrc, const int* __restrict__ edst,
                          int E, int Nn, int* __restrict__ cursor,
                          int* __restrict__ ssrc_sorted) {
    int e = blockIdx.x * blockDim.x + threadIdx.x;
    int Etot = E + Nn;
    if (e >= Etot) return;
    int s, d;
    if (e < E) { s = esrc[e]; d = edst[e]; }
    else       { s = e - E;   d = e - E; }
    int pos = atomicAdd(&cursor[d], 1);
    ssrc_sorted[pos] = s;
}

// ------- softmax stats + fused alpha write (coalesced): H=4 ----------------
__global__ __launch_bounds__(256) void stats1_k(
    const int* __restrict__ rowptr, const int* __restrict__ ssrc,
    const float* __restrict__ a_s, const float* __restrict__ a_d,
    __half2* __restrict__ alph, int Nn) {
    int n = (blockIdx.x * blockDim.x + threadIdx.x) >> 6;
    int lane = threadIdx.x & 63;
    if (n >= Nn) return;
    const int r0 = rowptr[n];
    const int deg = rowptr[n + 1] - r0;
    const float4 adn = ((const float4*)a_d)[n];

    float mx0 = -1e30f, mx1 = -1e30f, mx2 = -1e30f, mx3 = -1e30f;
    float sm0 = 0.f, sm1 = 0.f, sm2 = 0.f, sm3 = 0.f;
    for (int j = lane; j < deg; j += 64) {
        int s = ssrc[r0 + j];
        float4 as = ((const float4*)a_s)[s];
        float e0 = as.x + adn.x; e0 = (e0 > 0.f) ? e0 : 0.2f * e0;
        float e1 = as.y + adn.y; e1 = (e1 > 0.f) ? e1 : 0.2f * e1;
        float e2 = as.z + adn.z; e2 = (e2 > 0.f) ? e2 : 0.2f * e2;
        float e3 = as.w + adn.w; e3 = (e3 > 0.f) ? e3 : 0.2f * e3;
        float m;
        m = fmaxf(mx0, e0); sm0 = sm0 * __expf(mx0 - m) + __expf(e0 - m); mx0 = m;
        m = fmaxf(mx1, e1); sm1 = sm1 * __expf(mx1 - m) + __expf(e1 - m); mx1 = m;
        m = fmaxf(mx2, e2); sm2 = sm2 * __expf(mx2 - m) + __expf(e2 - m); mx2 = m;
        m = fmaxf(mx3, e3); sm3 = sm3 * __expf(mx3 - m) + __expf(e3 - m); mx3 = m;
    }
#pragma unroll
    for (int off = 32; off > 0; off >>= 1) {
        float m2, s2, m;
        m2 = __shfl_xor(mx0, off); s2 = __shfl_xor(sm0, off);
        m = fmaxf(mx0, m2); sm0 = sm0 * __expf(mx0 - m) + s2 * __expf(m2 - m); mx0 = m;
        m2 = __shfl_xor(mx1, off); s2 = __shfl_xor(sm1, off);
        m = fmaxf(mx1, m2); sm1 = sm1 * __expf(mx1 - m) + s2 * __expf(m2 - m); mx1 = m;
        m2 = __shfl_xor(mx2, off); s2 = __shfl_xor(sm2, off);
        m = fmaxf(mx2, m2); sm2 = sm2 * __expf(mx2 - m) + s2 * __expf(m2 - m); mx2 = m;
        m2 = __shfl_xor(mx3, off); s2 = __shfl_xor(sm3, off);
        m = fmaxf(mx3, m2); sm3 = sm3 * __expf(mx3 - m) + s2 * __expf(m2 - m); mx3 = m;
    }
    const float iv0 = 1.f / (sm0 + 1e-16f), iv1 = 1.f / (sm1 + 1e-16f);
    const float iv2 = 1.f / (sm2 + 1e-16f), iv3 = 1.f / (sm3 + 1e-16f);

    // pass 2: recompute e per edge, write alpha (8 B/edge, coalesced)
    for (int j = lane; j < deg; j += 64) {
        int s = ssrc[r0 + j];
        float4 as = ((const float4*)a_s)[s];
        float e0 = as.x + adn.x; e0 = (e0 > 0.f) ? e0 : 0.2f * e0;
        float e1 = as.y + adn.y; e1 = (e1 > 0.f) ? e1 : 0.2f * e1;
        float e2 = as.z + adn.z; e2 = (e2 > 0.f) ? e2 : 0.2f * e2;
        float e3 = as.w + adn.w; e3 = (e3 > 0.f) ? e3 : 0.2f * e3;
        __half2 p0 = __floats2half2_rn(__expf(e0 - mx0) * iv0, __expf(e1 - mx1) * iv1);
        __half2 p1 = __floats2half2_rn(__expf(e2 - mx2) * iv2, __expf(e3 - mx3) * iv3);
        alph[(size_t)(r0 + j) * 2]     = p0;
        alph[(size_t)(r0 + j) * 2 + 1] = p1;
    }
}

// ------- softmax stats + fused alpha write: H=1 ----------------------------
__global__ __launch_bounds__(256) void stats2_k(
    const int* __restrict__ rowptr, const int* __restrict__ ssrc,
    const float* __restrict__ a_s, const float* __restrict__ a_d,
    __half* __restrict__ alph, int Nn) {
    int n = (blockIdx.x * blockDim.x + threadIdx.x) >> 6;
    int lane = threadIdx.x & 63;
    if (n >= Nn) return;
    const int r0 = rowptr[n];
    const int deg = rowptr[n + 1] - r0;
    const float adn = a_d[n];
    float mx = -1e30f, sm = 0.f;
    for (int j = lane; j < deg; j += 64) {
        int s = ssrc[r0 + j];
        float e = a_s[s] + adn;
        e = (e > 0.f) ? e : 0.2f * e;
        float m = fmaxf(mx, e);
        sm = sm * __expf(mx - m) + __expf(e - m);
        mx = m;
    }
#pragma unroll
    for (int off = 32; off > 0; off >>= 1) {
        float m2 = __shfl_xor(mx, off);
        float s2 = __shfl_xor(sm, off);
        float m = fmaxf(mx, m2);
        sm = sm * __expf(mx - m) + s2 * __expf(m2 - m);
        mx = m;
    }
    const float inv = 1.f / (sm + 1e-16f);
    for (int j = lane; j < deg; j += 64) {
        int s = ssrc[r0 + j];
        float e = a_s[s] + adn;
        e = (e > 0.f) ? e : 0.2f * e;
        alph[r0 + j] = __float2half(__expf(e - mx) * inv);
    }
}

// ---------------- layer 1 aggregation: gather + FMA only -------------------
__global__ __launch_bounds__(256) void node_agg1_k(
    const int* __restrict__ rowptr, const int* __restrict__ ssrc,
    const __hip_bfloat16* __restrict__ xw, const __half* __restrict__ alph,
    const float* __restrict__ bias,
    const float* __restrict__ gamma, const float* __restrict__ beta,
    const float* __restrict__ mean, const float* __restrict__ var,
    __hip_bfloat16* __restrict__ out, int Nn) {
    int n = (blockIdx.x * blockDim.x + threadIdx.x) >> 6;
    int lane = threadIdx.x & 63;
    if (n >= Nn) return;
    const int r0 = rowptr[n];
    const int deg = rowptr[n + 1] - r0;
    const int h = lane >> 4;
    const __half* al = alph + (size_t)r0 * 4 + h;
    const int* sp = ssrc + r0;
    const __hip_bfloat162* xw2p = (const __hip_bfloat162*)xw;

    float accx = 0.f, accy = 0.f;
#pragma unroll 4
    for (int j = 0; j < deg; ++j) {
        int s = sp[j];
        float a = __half2float(al[(size_t)j * 4]);
        float2 f = __bfloat1622float2(xw2p[(size_t)s * 64 + lane]);
        accx += a * f.x;
        accy += a * f.y;
    }

    const int c = 2 * lane;
    float v0 = accx + bias[c];
    float v1 = accy + bias[c + 1];
    v0 = (v0 - mean[c])     * rsqrtf(var[c]     + 1e-5f) * gamma[c]     + beta[c];
    v1 = (v1 - mean[c + 1]) * rsqrtf(var[c + 1] + 1e-5f) * gamma[c + 1] + beta[c + 1];
    v0 = (v0 > 0.f) ? v0 : (__expf(v0) - 1.0f);
    v1 = (v1 > 0.f) ? v1 : (__expf(v1) - 1.0f);
    __hip_bfloat162* op = (__hip_bfloat162*)(out + (size_t)n * 128 + c);
    *op = __hip_bfloat162(__float2bfloat16(v0), __float2bfloat16(v1));
}

// ---------------- layer 2 aggregation --------------------------------------
__global__ __launch_bounds__(256) void node_agg2_k(
    const int* __restrict__ rowptr, const int* __restrict__ ssrc,
    const __hip_bfloat16* __restrict__ xw, const __half* __restrict__ alph,
    const float* __restrict__ bias, float* __restrict__ out, int Nn) {
    int n = (blockIdx.x * blockDim.x + threadIdx.x) >> 6;
    int lane = threadIdx.x & 63;
    if (n >= Nn) return;
    const int r0 = rowptr[n];
    const int deg = rowptr[n + 1] - r0;
    const int half = lane >> 5, li = lane & 31;
    const __hip_bfloat162* xw2p = (const __hip_bfloat162*)xw;

    float accx = 0.f, accy = 0.f;
#pragma unroll 2
    for (int j = 0; j < deg; j += 2) {
        int jj = j + half;
        bool ok = jj < deg;
        int s = ssrc[r0 + (ok ? jj : j)];
        float a = ok ? __half2float(alph[r0 + jj]) : 0.0f;
        float2 f = __bfloat1622float2(xw2p[(size_t)s * 32 + li]);
        accx += a * f.x;
        accy += a * f.y;
    }
    accx += __shfl_down(accx, 32);
    accy += __shfl_down(accy, 32);
    if (lane < 32) {
        const int c = 2 * li;
        float2* op = (float2*)(out + (size_t)n * 64 + c);
        *op = make_float2(accx + bias[c], accy + bias[c + 1]);
    }
}

extern "C" void kernel_launch(void* const* d_in, const int* in_sizes, int n_in,
                              void* d_out, int out_size, void* d_ws, size_t ws_size,
                              hipStream_t stream) {
    const float* x     = (const float*)d_in[0];
    const int*   ei    = (const int*)d_in[1];
    const float* W1    = (const float*)d_in[2];
    const float* as1   = (const float*)d_in[3];
    const float* ad1   = (const float*)d_in[4];
    const float* b1    = (const float*)d_in[5];
    const float* gamma = (const float*)d_in[6];
    const float* beta  = (const float*)d_in[7];
    const float* mean  = (const float*)d_in[8];
    const float* var   = (const float*)d_in[9];
    const float* W2    = (const float*)d_in[10];
    const float* as2   = (const float*)d_in[11];
    const float* ad2   = (const float*)d_in[12];
    const float* b2    = (const float*)d_in[13];
    float* out = (float*)d_out;

    const int N = NNODES;
    const int E = in_sizes[1] / 2;
    const int Etot = E + N;
    const int* esrc = ei;
    const int* edst = ei + E;

    // workspace layout (16-B aligned segments), ~48 MB total
    char* w = (char*)d_ws;
    __hip_bfloat16* xw1 = (__hip_bfloat16*)w; w += (size_t)N * 128 * 2;   // 12.8 MB
    __hip_bfloat16* hbuf = (__hip_bfloat16*)w; w += (size_t)N * 128 * 2;  // 12.8 MB
    __hip_bfloat16* xw2 = (__hip_bfloat16*)w; w += (size_t)N * 64 * 2;    // 6.4 MB
    float* a_s1 = (float*)w; w += (size_t)N * 4 * 4;   // also a_s2 (reuse)
    float* a_d1 = (float*)w; w += (size_t)N * 4 * 4;   // also a_d2 (reuse)
    __half* alpha1 = (__half*)w; w += (size_t)Etot * 4 * 2 + 16;  // 13.2 MB; also alpha2
    int* cnt    = (int*)w;   w += (size_t)N * 4;       // reused as cursor
    int* partial= (int*)w;   w += (size_t)N * 4;
    int* rowptr = (int*)w;   w += (size_t)(N + 8) * 4;
    int* bsum   = (int*)w;   w += 1024;
    int* ssrc_s = (int*)w;   w += (size_t)Etot * 4 + 16;   // 6.6 MB
    __hip_bfloat16* wp1 = (__hip_bfloat16*)w; w += 8 * 4 * 64 * 8 * 2;  // 32 KB
    __hip_bfloat16* wp2 = (__hip_bfloat16*)w; w += 4 * 4 * 64 * 8 * 2;  // 16 KB
    float* a_s2 = a_s1; float* a_d2 = a_d1;
    __half* alpha2 = alpha1;

    const int TB = 256;
    const int nb = (N + 255) / 256;
    const int edgeBlocks = (E + TB - 1) / TB;
    const int etotBlocks = (Etot + TB - 1) / TB;
    const int nodeBlocks = (N + TB - 1) / TB;
    const int aggBlocks  = (N + 3) / 4;            // one wave/node, 4 waves/block
    const int gemmBlocks = (N / 16 + 3) / 4;       // 3125 row-tiles / 4 waves

    // ---- W repack (independent) ----
    wpack_k<128><<<(8 * 4 * 64 + TB - 1) / TB, TB, 0, stream>>>(W1, wp1);
    wpack_k<64><<<(4 * 4 * 64 + TB - 1) / TB, TB, 0, stream>>>(W2, wp2);

    // ---- CSR build (shared by both layers) ----
    init_cnt_k<<<nodeBlocks, TB, 0, stream>>>(cnt, N);
    hist_k<<<edgeBlocks, TB, 0, stream>>>(edst, E, cnt);
    scan1_k<<<nb, TB, 0, stream>>>(cnt, partial, bsum, N);
    scan2_k<<<1, TB, 0, stream>>>(bsum, nb);
    scan3_k<<<nb, TB, 0, stream>>>(partial, bsum, rowptr, N);
    cursor_k<<<nodeBlocks, TB, 0, stream>>>(rowptr, cnt, N);
    scatter_k<<<etotBlocks, TB, 0, stream>>>(esrc, edst, E, N, cnt, ssrc_s);

    // ---- layer 1 ----
    gemm_mfma_k<128, false><<<gemmBlocks, TB, 0, stream>>>(x, wp1, xw1, N);
    attn_scores_k<4, 32><<<(N * 4 + TB - 1) / TB, TB, 0, stream>>>(xw1, as1, ad1, a_s1, a_d1, N * 4);
    stats1_k<<<aggBlocks, TB, 0, stream>>>(rowptr, ssrc_s, a_s1, a_d1, (__half2*)alpha1, N);
    node_agg1_k<<<aggBlocks, TB, 0, stream>>>(rowptr, ssrc_s, xw1, alpha1,
                                              b1, gamma, beta, mean, var, hbuf, N);

    // ---- layer 2 ----
    gemm_mfma_k<64, true><<<gemmBlocks, TB, 0, stream>>>(hbuf, wp2, xw2, N);
    attn_scores_k<1, 64><<<(N + TB - 1) / TB, TB, 0, stream>>>(xw2, as2, ad2, a_s2, a_d2, N);
    stats2_k<<<aggBlocks, TB, 0, stream>>>(rowptr, ssrc_s, a_s2, a_d2, alpha2, N);
    node_agg2_k<<<aggBlocks, TB, 0, stream>>>(rowptr, ssrc_s, xw2, alpha2, b2, out, N);
}

// Round 6
// 387.186 us; speedup vs baseline: 5.3030x; 1.3645x over previous
//
#include <hip/hip_runtime.h>
#include <hip/hip_bf16.h>
#include <hip/hip_fp16.h>

// ---------------------------------------------------------------------------
// GAT 2-layer pipeline. R6: CSR build via bucketed counting sort (LDS
// histograms, no global atomics, coalesced final writes, ushort src ids).
// MFMA bf16 GEMMs, fused alpha in stats kernels, gather-only aggregation.
// ---------------------------------------------------------------------------

#define NNODES 50000
#define NODE_SHIFT 7                       // 128 nodes per bucket
#define BKTS ((NNODES + 127) / 128)        // 391
#define CHUNK 16384                        // edges per histogram block
#define CAP 8192                           // max edges per bucket (mean ~4224)

typedef __bf16 bf16x8 __attribute__((ext_vector_type(8)));
typedef float f32x4 __attribute__((ext_vector_type(4)));

// ------------------------- W repack to MFMA B-fragment ----------------------
template <int COLS>
__global__ void wpack_k(const float* __restrict__ W, __hip_bfloat16* __restrict__ Wp) {
    constexpr int TOT = (COLS / 16) * 4 * 64;
    int i = blockIdx.x * blockDim.x + threadIdx.x;
    if (i >= TOT) return;
    int l = i & 63, s = (i >> 6) & 3, t = i >> 8;
    int quad = l >> 4, col = l & 15;
#pragma unroll
    for (int j = 0; j < 8; ++j) {
        float f = W[(s * 32 + quad * 8 + j) * COLS + t * 16 + col];
        Wp[(size_t)i * 8 + j] = __float2bfloat16(f);
    }
}

// ------------------------- MFMA GEMM: Y = X @ W -----------------------------
template <int COLS, bool IN_BF16>
__global__ __launch_bounds__(256) void gemm_mfma_k(const void* __restrict__ Xv,
                                                   const __hip_bfloat16* __restrict__ Wp,
                                                   __hip_bfloat16* __restrict__ Y, int M) {
    const int wid = threadIdx.x >> 6, lane = threadIdx.x & 63;
    const int tile = blockIdx.x * 4 + wid;
    if (tile * 16 >= M) return;
    const int quad = lane >> 4, col = lane & 15;
    const int row = tile * 16 + col;

    bf16x8 afr[4];
    if (IN_BF16) {
        const __hip_bfloat16* X = (const __hip_bfloat16*)Xv;
#pragma unroll
        for (int s = 0; s < 4; ++s)
            afr[s] = *(const bf16x8*)(X + (size_t)row * 128 + s * 32 + quad * 8);
    } else {
        const float* X = (const float*)Xv;
#pragma unroll
        for (int s = 0; s < 4; ++s) {
            const float4* p = (const float4*)(X + (size_t)row * 128 + s * 32 + quad * 8);
            float4 f0 = p[0], f1 = p[1];
            afr[s][0] = (__bf16)f0.x; afr[s][1] = (__bf16)f0.y;
            afr[s][2] = (__bf16)f0.z; afr[s][3] = (__bf16)f0.w;
            afr[s][4] = (__bf16)f1.x; afr[s][5] = (__bf16)f1.y;
            afr[s][6] = (__bf16)f1.z; afr[s][7] = (__bf16)f1.w;
        }
    }

    const bf16x8* Wp8 = (const bf16x8*)Wp;
#pragma unroll
    for (int t = 0; t < COLS / 16; ++t) {
        f32x4 acc = {0.f, 0.f, 0.f, 0.f};
#pragma unroll
        for (int s = 0; s < 4; ++s) {
            bf16x8 bfr = Wp8[(t * 4 + s) * 64 + lane];
            acc = __builtin_amdgcn_mfma_f32_16x16x32_bf16(afr[s], bfr, acc, 0, 0, 0);
        }
#pragma unroll
        for (int r = 0; r < 4; ++r)
            Y[(size_t)(tile * 16 + quad * 4 + r) * COLS + t * 16 + col] =
                __float2bfloat16(acc[r]);
    }
}

// a_src[n,h] = sum_c xw[n,h,c]*att_src[h,c]; one thread per (n,h); xw is bf16
template <int H, int C>
__global__ void attn_scores_k(const __hip_bfloat16* __restrict__ xw,
                              const float* __restrict__ atts,
                              const float* __restrict__ attd,
                              float* __restrict__ a_s, float* __restrict__ a_d,
                              int NH) {
    int i = blockIdx.x * blockDim.x + threadIdx.x;  // i = n*H + h
    if (i >= NH) return;
    const int h = i % H;
    const __hip_bfloat162* row2 = (const __hip_bfloat162*)(xw + (size_t)i * C);
    const float* ps = atts + h * C;
    const float* pd = attd + h * C;
    float as = 0.0f, ad = 0.0f;
#pragma unroll
    for (int c2 = 0; c2 < C / 2; ++c2) {
        float2 f = __bfloat1622float2(row2[c2]);
        as += f.x * ps[2 * c2] + f.y * ps[2 * c2 + 1];
        ad += f.x * pd[2 * c2] + f.y * pd[2 * c2 + 1];
    }
    a_s[i] = as;
    a_d[i] = ad;
}

// ------------------- CSR build: bucketed counting sort ----------------------
// Pass A: per-chunk LDS histogram over BKTS buckets -> g_hist[b*NB + blk]
__global__ __launch_bounds__(256) void hist_bucket_k(const int* __restrict__ edst,
                                                     int E, int Etot, int NB,
                                                     int* __restrict__ g_hist) {
    __shared__ int h[BKTS];
    for (int b = threadIdx.x; b < BKTS; b += 256) h[b] = 0;
    __syncthreads();
    const int e0 = blockIdx.x * CHUNK;
    const int e1 = min(e0 + CHUNK, Etot);
    for (int i = e0 + threadIdx.x; i < e1; i += 256) {
        int d = (i < E) ? edst[i] : (i - E);
        atomicAdd(&h[d >> NODE_SHIFT], 1);
    }
    __syncthreads();
    for (int b = threadIdx.x; b < BKTS; b += 256)
        g_hist[b * NB + blockIdx.x] = h[b];
}

// generic block scans (reused for the flat bucket-major histogram)
__global__ __launch_bounds__(256) void scan1_k(const int* __restrict__ cnt,
                                               int* __restrict__ partial,
                                               int* __restrict__ bsum, int Nn) {
    __shared__ int sA[256];
    int i = blockIdx.x * 256 + threadIdx.x;
    sA[threadIdx.x] = (i < Nn) ? cnt[i] : 0;
    __syncthreads();
    for (int off = 1; off < 256; off <<= 1) {
        int u = (threadIdx.x >= off) ? sA[threadIdx.x - off] : 0;
        __syncthreads();
        sA[threadIdx.x] += u;
        __syncthreads();
    }
    if (i < Nn) partial[i] = sA[threadIdx.x];
    if (threadIdx.x == 255) bsum[blockIdx.x] = sA[255];
}

__global__ __launch_bounds__(256) void scan2_k(int* __restrict__ bsum, int nb) {
    __shared__ int sA[256];
    int t = threadIdx.x;
    sA[t] = (t < nb) ? bsum[t] : 0;
    __syncthreads();
    for (int off = 1; off < 256; off <<= 1) {
        int u = (t >= off) ? sA[t - off] : 0;
        __syncthreads();
        sA[t] += u;
        __syncthreads();
    }
    if (t < nb) bsum[t] = sA[t];
}

// out[i] = exclusive prefix; out must have Nn+1 entries
__global__ void scan3_k(const int* __restrict__ partial, const int* __restrict__ bsum,
                        int* __restrict__ out, int Nn) {
    int i = blockIdx.x * 256 + threadIdx.x;
    if (i >= Nn) return;
    int b = blockIdx.x;
    int off = (b == 0) ? 0 : bsum[b - 1];
    out[i + 1] = partial[i] + off;
    if (i == 0) out[0] = 0;
}

// Pass B: partition edges into buckets; packed key = (dlow<<16)|src.
// Writes per (block,bucket) are contiguous runs; cursors live in LDS.
__global__ __launch_bounds__(256) void scatter_bucket_k(
    const int* __restrict__ esrc, const int* __restrict__ edst,
    int E, int Etot, int NB, const int* __restrict__ scanned,
    unsigned int* __restrict__ gbucket) {
    __shared__ int cur[BKTS];
    for (int b = threadIdx.x; b < BKTS; b += 256)
        cur[b] = scanned[b * NB + blockIdx.x];
    __syncthreads();
    const int e0 = blockIdx.x * CHUNK;
    const int e1 = min(e0 + CHUNK, Etot);
    for (int i = e0 + threadIdx.x; i < e1; i += 256) {
        int s, d;
        if (i < E) { s = esrc[i]; d = edst[i]; }
        else       { s = i - E;   d = i - E; }
        int pos = atomicAdd(&cur[d >> NODE_SHIFT], 1);
        gbucket[pos] = ((unsigned)(d & 127) << 16) | (unsigned)s;
    }
}

// Pass C: one block per bucket. LDS counting sort over the bucket's 128 nodes;
// write ssrc (ushort, coalesced region) and rowptr.
__global__ __launch_bounds__(256) void finalize_k(
    const unsigned int* __restrict__ gbucket, const int* __restrict__ scanned,
    int NB, int Etot, unsigned short* __restrict__ ssrc,
    int* __restrict__ rowptr, int Nn) {
    const int b = blockIdx.x;
    const int base = scanned[b * NB];
    const int end = (b + 1 < BKTS) ? scanned[(b + 1) * NB] : Etot;
    const int cnt = end - base;
    const int t = threadIdx.x;

    __shared__ unsigned int keys[CAP];
    __shared__ int hist[128], sA[128], cur[128];

    for (int i = t; i < cnt; i += 256) keys[i] = gbucket[base + i];
    if (t < 128) hist[t] = 0;
    __syncthreads();
    for (int i = t; i < cnt; i += 256) atomicAdd(&hist[keys[i] >> 16], 1);
    __syncthreads();
    if (t < 128) sA[t] = hist[t];
    __syncthreads();
    for (int off = 1; off < 128; off <<= 1) {
        int u = 0;
        if (t < 128 && t >= off) u = sA[t - off];
        __syncthreads();
        if (t < 128) sA[t] += u;
        __syncthreads();
    }
    // exclusive prefix
    if (t < 128) {
        int excl = sA[t] - hist[t];
        cur[t] = excl;
        int node = b * 128 + t;
        if (node <= Nn) rowptr[node] = base + excl;
    }
    __syncthreads();
    for (int i = t; i < cnt; i += 256) {
        unsigned k = keys[i];
        int p = atomicAdd(&cur[k >> 16], 1);
        ssrc[base + p] = (unsigned short)(k & 0xFFFFu);
    }
    // last bucket thread sets rowptr[N] (node == Nn handled above when t==Nn-b*128)
    if (b == BKTS - 1 && t == 128 + 0) { /* no-op */ }
}

__global__ void rowptr_tail_k(int* __restrict__ rowptr, int Nn, int Etot) {
    if (blockIdx.x == 0 && threadIdx.x == 0) rowptr[Nn] = Etot;
}

// ------- softmax stats + fused alpha write (coalesced): H=4 ----------------
__global__ __launch_bounds__(256) void stats1_k(
    const int* __restrict__ rowptr, const unsigned short* __restrict__ ssrc,
    const float* __restrict__ a_s, const float* __restrict__ a_d,
    __half2* __restrict__ alph, int Nn) {
    int n = (blockIdx.x * blockDim.x + threadIdx.x) >> 6;
    int lane = threadIdx.x & 63;
    if (n >= Nn) return;
    const int r0 = rowptr[n];
    const int deg = rowptr[n + 1] - r0;
    const float4 adn = ((const float4*)a_d)[n];

    float mx0 = -1e30f, mx1 = -1e30f, mx2 = -1e30f, mx3 = -1e30f;
    float sm0 = 0.f, sm1 = 0.f, sm2 = 0.f, sm3 = 0.f;
    for (int j = lane; j < deg; j += 64) {
        int s = ssrc[r0 + j];
        float4 as = ((const float4*)a_s)[s];
        float e0 = as.x + adn.x; e0 = (e0 > 0.f) ? e0 : 0.2f * e0;
        float e1 = as.y + adn.y; e1 = (e1 > 0.f) ? e1 : 0.2f * e1;
        float e2 = as.z + adn.z; e2 = (e2 > 0.f) ? e2 : 0.2f * e2;
        float e3 = as.w + adn.w; e3 = (e3 > 0.f) ? e3 : 0.2f * e3;
        float m;
        m = fmaxf(mx0, e0); sm0 = sm0 * __expf(mx0 - m) + __expf(e0 - m); mx0 = m;
        m = fmaxf(mx1, e1); sm1 = sm1 * __expf(mx1 - m) + __expf(e1 - m); mx1 = m;
        m = fmaxf(mx2, e2); sm2 = sm2 * __expf(mx2 - m) + __expf(e2 - m); mx2 = m;
        m = fmaxf(mx3, e3); sm3 = sm3 * __expf(mx3 - m) + __expf(e3 - m); mx3 = m;
    }
#pragma unroll
    for (int off = 32; off > 0; off >>= 1) {
        float m2, s2, m;
        m2 = __shfl_xor(mx0, off); s2 = __shfl_xor(sm0, off);
        m = fmaxf(mx0, m2); sm0 = sm0 * __expf(mx0 - m) + s2 * __expf(m2 - m); mx0 = m;
        m2 = __shfl_xor(mx1, off); s2 = __shfl_xor(sm1, off);
        m = fmaxf(mx1, m2); sm1 = sm1 * __expf(mx1 - m) + s2 * __expf(m2 - m); mx1 = m;
        m2 = __shfl_xor(mx2, off); s2 = __shfl_xor(sm2, off);
        m = fmaxf(mx2, m2); sm2 = sm2 * __expf(mx2 - m) + s2 * __expf(m2 - m); mx2 = m;
        m2 = __shfl_xor(mx3, off); s2 = __shfl_xor(sm3, off);
        m = fmaxf(mx3, m2); sm3 = sm3 * __expf(mx3 - m) + s2 * __expf(m2 - m); mx3 = m;
    }
    const float iv0 = 1.f / (sm0 + 1e-16f), iv1 = 1.f / (sm1 + 1e-16f);
    const float iv2 = 1.f / (sm2 + 1e-16f), iv3 = 1.f / (sm3 + 1e-16f);

    for (int j = lane; j < deg; j += 64) {
        int s = ssrc[r0 + j];
        float4 as = ((const float4*)a_s)[s];
        float e0 = as.x + adn.x; e0 = (e0 > 0.f) ? e0 : 0.2f * e0;
        float e1 = as.y + adn.y; e1 = (e1 > 0.f) ? e1 : 0.2f * e1;
        float e2 = as.z + adn.z; e2 = (e2 > 0.f) ? e2 : 0.2f * e2;
        float e3 = as.w + adn.w; e3 = (e3 > 0.f) ? e3 : 0.2f * e3;
        __half2 p0 = __floats2half2_rn(__expf(e0 - mx0) * iv0, __expf(e1 - mx1) * iv1);
        __half2 p1 = __floats2half2_rn(__expf(e2 - mx2) * iv2, __expf(e3 - mx3) * iv3);
        alph[(size_t)(r0 + j) * 2]     = p0;
        alph[(size_t)(r0 + j) * 2 + 1] = p1;
    }
}

// ------- softmax stats + fused alpha write: H=1 ----------------------------
__global__ __launch_bounds__(256) void stats2_k(
    const int* __restrict__ rowptr, const unsigned short* __restrict__ ssrc,
    const float* __restrict__ a_s, const float* __restrict__ a_d,
    __half* __restrict__ alph, int Nn) {
    int n = (blockIdx.x * blockDim.x + threadIdx.x) >> 6;
    int lane = threadIdx.x & 63;
    if (n >= Nn) return;
    const int r0 = rowptr[n];
    const int deg = rowptr[n + 1] - r0;
    const float adn = a_d[n];
    float mx = -1e30f, sm = 0.f;
    for (int j = lane; j < deg; j += 64) {
        int s = ssrc[r0 + j];
        float e = a_s[s] + adn;
        e = (e > 0.f) ? e : 0.2f * e;
        float m = fmaxf(mx, e);
        sm = sm * __expf(mx - m) + __expf(e - m);
        mx = m;
    }
#pragma unroll
    for (int off = 32; off > 0; off >>= 1) {
        float m2 = __shfl_xor(mx, off);
        float s2 = __shfl_xor(sm, off);
        float m = fmaxf(mx, m2);
        sm = sm * __expf(mx - m) + s2 * __expf(m2 - m);
        mx = m;
    }
    const float inv = 1.f / (sm + 1e-16f);
    for (int j = lane; j < deg; j += 64) {
        int s = ssrc[r0 + j];
        float e = a_s[s] + adn;
        e = (e > 0.f) ? e : 0.2f * e;
        alph[r0 + j] = __float2half(__expf(e - mx) * inv);
    }
}

// ---------------- layer 1 aggregation: gather + FMA only -------------------
__global__ __launch_bounds__(256) void node_agg1_k(
    const int* __restrict__ rowptr, const unsigned short* __restrict__ ssrc,
    const __hip_bfloat16* __restrict__ xw, const __half* __restrict__ alph,
    const float* __restrict__ bias,
    const float* __restrict__ gamma, const float* __restrict__ beta,
    const float* __restrict__ mean, const float* __restrict__ var,
    __hip_bfloat16* __restrict__ out, int Nn) {
    int n = (blockIdx.x * blockDim.x + threadIdx.x) >> 6;
    int lane = threadIdx.x & 63;
    if (n >= Nn) return;
    const int r0 = rowptr[n];
    const int deg = rowptr[n + 1] - r0;
    const int h = lane >> 4;
    const __half* al = alph + (size_t)r0 * 4 + h;
    const unsigned short* sp = ssrc + r0;
    const __hip_bfloat162* xw2p = (const __hip_bfloat162*)xw;

    float accx = 0.f, accy = 0.f;
#pragma unroll 4
    for (int j = 0; j < deg; ++j) {
        int s = sp[j];
        float a = __half2float(al[(size_t)j * 4]);
        float2 f = __bfloat1622float2(xw2p[(size_t)s * 64 + lane]);
        accx += a * f.x;
        accy += a * f.y;
    }

    const int c = 2 * lane;
    float v0 = accx + bias[c];
    float v1 = accy + bias[c + 1];
    v0 = (v0 - mean[c])     * rsqrtf(var[c]     + 1e-5f) * gamma[c]     + beta[c];
    v1 = (v1 - mean[c + 1]) * rsqrtf(var[c + 1] + 1e-5f) * gamma[c + 1] + beta[c + 1];
    v0 = (v0 > 0.f) ? v0 : (__expf(v0) - 1.0f);
    v1 = (v1 > 0.f) ? v1 : (__expf(v1) - 1.0f);
    __hip_bfloat162* op = (__hip_bfloat162*)(out + (size_t)n * 128 + c);
    *op = __hip_bfloat162(__float2bfloat16(v0), __float2bfloat16(v1));
}

// ---------------- layer 2 aggregation --------------------------------------
__global__ __launch_bounds__(256) void node_agg2_k(
    const int* __restrict__ rowptr, const unsigned short* __restrict__ ssrc,
    const __hip_bfloat16* __restrict__ xw, const __half* __restrict__ alph,
    const float* __restrict__ bias, float* __restrict__ out, int Nn) {
    int n = (blockIdx.x * blockDim.x + threadIdx.x) >> 6;
    int lane = threadIdx.x & 63;
    if (n >= Nn) return;
    const int r0 = rowptr[n];
    const int deg = rowptr[n + 1] - r0;
    const int half = lane >> 5, li = lane & 31;
    const __hip_bfloat162* xw2p = (const __hip_bfloat162*)xw;

    float accx = 0.f, accy = 0.f;
#pragma unroll 2
    for (int j = 0; j < deg; j += 2) {
        int jj = j + half;
        bool ok = jj < deg;
        int s = ssrc[r0 + (ok ? jj : j)];
        float a = ok ? __half2float(alph[r0 + jj]) : 0.0f;
        float2 f = __bfloat1622float2(xw2p[(size_t)s * 32 + li]);
        accx += a * f.x;
        accy += a * f.y;
    }
    accx += __shfl_down(accx, 32);
    accy += __shfl_down(accy, 32);
    if (lane < 32) {
        const int c = 2 * li;
        float2* op = (float2*)(out + (size_t)n * 64 + c);
        *op = make_float2(accx + bias[c], accy + bias[c + 1]);
    }
}

extern "C" void kernel_launch(void* const* d_in, const int* in_sizes, int n_in,
                              void* d_out, int out_size, void* d_ws, size_t ws_size,
                              hipStream_t stream) {
    const float* x     = (const float*)d_in[0];
    const int*   ei    = (const int*)d_in[1];
    const float* W1    = (const float*)d_in[2];
    const float* as1   = (const float*)d_in[3];
    const float* ad1   = (const float*)d_in[4];
    const float* b1    = (const float*)d_in[5];
    const float* gamma = (const float*)d_in[6];
    const float* beta  = (const float*)d_in[7];
    const float* mean  = (const float*)d_in[8];
    const float* var   = (const float*)d_in[9];
    const float* W2    = (const float*)d_in[10];
    const float* as2   = (const float*)d_in[11];
    const float* ad2   = (const float*)d_in[12];
    const float* b2    = (const float*)d_in[13];
    float* out = (float*)d_out;

    const int N = NNODES;
    const int E = in_sizes[1] / 2;
    const int Etot = E + N;
    const int* esrc = ei;
    const int* edst = ei + E;

    const int NB = (Etot + CHUNK - 1) / CHUNK;          // histogram blocks
    const int flatN = BKTS * NB;                        // bucket-major hist size

    // workspace layout (16-B aligned segments), ~58 MB total
    char* w = (char*)d_ws;
    __hip_bfloat16* xw1 = (__hip_bfloat16*)w; w += (size_t)N * 128 * 2;   // 12.8 MB
    __hip_bfloat16* hbuf = (__hip_bfloat16*)w; w += (size_t)N * 128 * 2;  // 12.8 MB
    __hip_bfloat16* xw2 = (__hip_bfloat16*)w; w += (size_t)N * 64 * 2;    // 6.4 MB
    float* a_s1 = (float*)w; w += (size_t)N * 4 * 4;   // also a_s2 (reuse)
    float* a_d1 = (float*)w; w += (size_t)N * 4 * 4;   // also a_d2 (reuse)
    __half* alpha1 = (__half*)w; w += (size_t)Etot * 4 * 2 + 16;  // 13.2 MB; also alpha2
    unsigned int* gbucket = (unsigned int*)w; w += (size_t)Etot * 4 + 16; // 6.6 MB
    int* g_hist  = (int*)w;  w += (size_t)flatN * 4 + 16;
    int* partial = (int*)w;  w += (size_t)flatN * 4 + 16;
    int* scanned = (int*)w;  w += (size_t)(flatN + 4) * 4 + 16;
    int* bsum    = (int*)w;  w += 1024;
    int* rowptr  = (int*)w;  w += (size_t)(N + 8) * 4;
    unsigned short* ssrc_s = (unsigned short*)w; w += (size_t)Etot * 2 + 16; // 3.3 MB
    __hip_bfloat16* wp1 = (__hip_bfloat16*)w; w += 8 * 4 * 64 * 8 * 2;  // 32 KB
    __hip_bfloat16* wp2 = (__hip_bfloat16*)w; w += 4 * 4 * 64 * 8 * 2;  // 16 KB
    float* a_s2 = a_s1; float* a_d2 = a_d1;
    __half* alpha2 = alpha1;

    const int TB = 256;
    const int nb2 = (flatN + 255) / 256;           // scan blocks (<=256)
    const int aggBlocks  = (N + 3) / 4;            // one wave/node, 4 waves/block
    const int gemmBlocks = (N / 16 + 3) / 4;       // 3125 row-tiles / 4 waves

    // ---- W repack (independent) ----
    wpack_k<128><<<(8 * 4 * 64 + TB - 1) / TB, TB, 0, stream>>>(W1, wp1);
    wpack_k<64><<<(4 * 4 * 64 + TB - 1) / TB, TB, 0, stream>>>(W2, wp2);

    // ---- CSR build: bucketed counting sort ----
    hist_bucket_k<<<NB, TB, 0, stream>>>(edst, E, Etot, NB, g_hist);
    scan1_k<<<nb2, TB, 0, stream>>>(g_hist, partial, bsum, flatN);
    scan2_k<<<1, TB, 0, stream>>>(bsum, nb2);
    scan3_k<<<nb2, TB, 0, stream>>>(partial, bsum, scanned, flatN);
    scatter_bucket_k<<<NB, TB, 0, stream>>>(esrc, edst, E, Etot, NB, scanned, gbucket);
    finalize_k<<<BKTS, TB, 0, stream>>>(gbucket, scanned, NB, Etot, ssrc_s, rowptr, N);
    rowptr_tail_k<<<1, 64, 0, stream>>>(rowptr, N, Etot);

    // ---- layer 1 ----
    gemm_mfma_k<128, false><<<gemmBlocks, TB, 0, stream>>>(x, wp1, xw1, N);
    attn_scores_k<4, 32><<<(N * 4 + TB - 1) / TB, TB, 0, stream>>>(xw1, as1, ad1, a_s1, a_d1, N * 4);
    stats1_k<<<aggBlocks, TB, 0, stream>>>(rowptr, ssrc_s, a_s1, a_d1, (__half2*)alpha1, N);
    node_agg1_k<<<aggBlocks, TB, 0, stream>>>(rowptr, ssrc_s, xw1, alpha1,
                                              b1, gamma, beta, mean, var, hbuf, N);

    // ---- layer 2 ----
    gemm_mfma_k<64, true><<<gemmBlocks, TB, 0, stream>>>(hbuf, wp2, xw2, N);
    attn_scores_k<1, 64><<<(N + TB - 1) / TB, TB, 0, stream>>>(xw2, as2, ad2, a_s2, a_d2, N);
    stats2_k<<<aggBlocks, TB, 0, stream>>>(rowptr, ssrc_s, a_s2, a_d2, alpha2, N);
    node_agg2_k<<<aggBlocks, TB, 0, stream>>>(rowptr, ssrc_s, xw2, alpha2, b2, out, N);
}

// Round 7
// 309.539 us; speedup vs baseline: 6.6332x; 1.2508x over previous
//
#include <hip/hip_runtime.h>
#include <hip/hip_bf16.h>
#include <hip/hip_fp16.h>

// ---------------------------------------------------------------------------
// GAT 2-layer pipeline. R7: flash-style online softmax fused directly into
// the aggregation kernels (stats/alpha kernels+arrays eliminated); multi-edge
// ILP (2 edges/wave-iter layer1, 4 edges/wave-iter layer2) with shuffle merge.
// CSR via bucketed counting sort (LDS histograms, no global atomics).
// MFMA bf16 GEMMs.
// ---------------------------------------------------------------------------

#define NNODES 50000
#define NODE_SHIFT 7                       // 128 nodes per bucket
#define BKTS ((NNODES + 127) / 128)        // 391
#define CHUNK 16384                        // edges per histogram block
#define CAP 8192                           // max edges per bucket (mean ~4224)

typedef __bf16 bf16x8 __attribute__((ext_vector_type(8)));
typedef __bf16 bf16x4 __attribute__((ext_vector_type(4)));
typedef float f32x4 __attribute__((ext_vector_type(4)));

// ------------------------- W repack to MFMA B-fragment ----------------------
template <int COLS>
__global__ void wpack_k(const float* __restrict__ W, __hip_bfloat16* __restrict__ Wp) {
    constexpr int TOT = (COLS / 16) * 4 * 64;
    int i = blockIdx.x * blockDim.x + threadIdx.x;
    if (i >= TOT) return;
    int l = i & 63, s = (i >> 6) & 3, t = i >> 8;
    int quad = l >> 4, col = l & 15;
#pragma unroll
    for (int j = 0; j < 8; ++j) {
        float f = W[(s * 32 + quad * 8 + j) * COLS + t * 16 + col];
        Wp[(size_t)i * 8 + j] = __float2bfloat16(f);
    }
}

// ------------------------- MFMA GEMM: Y = X @ W -----------------------------
template <int COLS, bool IN_BF16>
__global__ __launch_bounds__(256) void gemm_mfma_k(const void* __restrict__ Xv,
                                                   const __hip_bfloat16* __restrict__ Wp,
                                                   __hip_bfloat16* __restrict__ Y, int M) {
    const int wid = threadIdx.x >> 6, lane = threadIdx.x & 63;
    const int tile = blockIdx.x * 4 + wid;
    if (tile * 16 >= M) return;
    const int quad = lane >> 4, col = lane & 15;
    const int row = tile * 16 + col;

    bf16x8 afr[4];
    if (IN_BF16) {
        const __hip_bfloat16* X = (const __hip_bfloat16*)Xv;
#pragma unroll
        for (int s = 0; s < 4; ++s)
            afr[s] = *(const bf16x8*)(X + (size_t)row * 128 + s * 32 + quad * 8);
    } else {
        const float* X = (const float*)Xv;
#pragma unroll
        for (int s = 0; s < 4; ++s) {
            const float4* p = (const float4*)(X + (size_t)row * 128 + s * 32 + quad * 8);
            float4 f0 = p[0], f1 = p[1];
            afr[s][0] = (__bf16)f0.x; afr[s][1] = (__bf16)f0.y;
            afr[s][2] = (__bf16)f0.z; afr[s][3] = (__bf16)f0.w;
            afr[s][4] = (__bf16)f1.x; afr[s][5] = (__bf16)f1.y;
            afr[s][6] = (__bf16)f1.z; afr[s][7] = (__bf16)f1.w;
        }
    }

    const bf16x8* Wp8 = (const bf16x8*)Wp;
#pragma unroll
    for (int t = 0; t < COLS / 16; ++t) {
        f32x4 acc = {0.f, 0.f, 0.f, 0.f};
#pragma unroll
        for (int s = 0; s < 4; ++s) {
            bf16x8 bfr = Wp8[(t * 4 + s) * 64 + lane];
            acc = __builtin_amdgcn_mfma_f32_16x16x32_bf16(afr[s], bfr, acc, 0, 0, 0);
        }
#pragma unroll
        for (int r = 0; r < 4; ++r)
            Y[(size_t)(tile * 16 + quad * 4 + r) * COLS + t * 16 + col] =
                __float2bfloat16(acc[r]);
    }
}

// a_src[n,h] = sum_c xw[n,h,c]*att_src[h,c]; one thread per (n,h); xw is bf16
template <int H, int C>
__global__ void attn_scores_k(const __hip_bfloat16* __restrict__ xw,
                              const float* __restrict__ atts,
                              const float* __restrict__ attd,
                              float* __restrict__ a_s, float* __restrict__ a_d,
                              int NH) {
    int i = blockIdx.x * blockDim.x + threadIdx.x;  // i = n*H + h
    if (i >= NH) return;
    const int h = i % H;
    const __hip_bfloat162* row2 = (const __hip_bfloat162*)(xw + (size_t)i * C);
    const float* ps = atts + h * C;
    const float* pd = attd + h * C;
    float as = 0.0f, ad = 0.0f;
#pragma unroll
    for (int c2 = 0; c2 < C / 2; ++c2) {
        float2 f = __bfloat1622float2(row2[c2]);
        as += f.x * ps[2 * c2] + f.y * ps[2 * c2 + 1];
        ad += f.x * pd[2 * c2] + f.y * pd[2 * c2 + 1];
    }
    a_s[i] = as;
    a_d[i] = ad;
}

// ------------------- CSR build: bucketed counting sort ----------------------
__global__ __launch_bounds__(256) void hist_bucket_k(const int* __restrict__ edst,
                                                     int E, int Etot, int NB,
                                                     int* __restrict__ g_hist) {
    __shared__ int h[BKTS];
    for (int b = threadIdx.x; b < BKTS; b += 256) h[b] = 0;
    __syncthreads();
    const int e0 = blockIdx.x * CHUNK;
    const int e1 = min(e0 + CHUNK, Etot);
    for (int i = e0 + threadIdx.x; i < e1; i += 256) {
        int d = (i < E) ? edst[i] : (i - E);
        atomicAdd(&h[d >> NODE_SHIFT], 1);
    }
    __syncthreads();
    for (int b = threadIdx.x; b < BKTS; b += 256)
        g_hist[b * NB + blockIdx.x] = h[b];
}

__global__ __launch_bounds__(256) void scan1_k(const int* __restrict__ cnt,
                                               int* __restrict__ partial,
                                               int* __restrict__ bsum, int Nn) {
    __shared__ int sA[256];
    int i = blockIdx.x * 256 + threadIdx.x;
    sA[threadIdx.x] = (i < Nn) ? cnt[i] : 0;
    __syncthreads();
    for (int off = 1; off < 256; off <<= 1) {
        int u = (threadIdx.x >= off) ? sA[threadIdx.x - off] : 0;
        __syncthreads();
        sA[threadIdx.x] += u;
        __syncthreads();
    }
    if (i < Nn) partial[i] = sA[threadIdx.x];
    if (threadIdx.x == 255) bsum[blockIdx.x] = sA[255];
}

__global__ __launch_bounds__(256) void scan2_k(int* __restrict__ bsum, int nb) {
    __shared__ int sA[256];
    int t = threadIdx.x;
    sA[t] = (t < nb) ? bsum[t] : 0;
    __syncthreads();
    for (int off = 1; off < 256; off <<= 1) {
        int u = (t >= off) ? sA[t - off] : 0;
        __syncthreads();
        sA[t] += u;
        __syncthreads();
    }
    if (t < nb) bsum[t] = sA[t];
}

__global__ void scan3_k(const int* __restrict__ partial, const int* __restrict__ bsum,
                        int* __restrict__ out, int Nn) {
    int i = blockIdx.x * 256 + threadIdx.x;
    if (i >= Nn) return;
    int b = blockIdx.x;
    int off = (b == 0) ? 0 : bsum[b - 1];
    out[i + 1] = partial[i] + off;
    if (i == 0) out[0] = 0;
}

__global__ __launch_bounds__(256) void scatter_bucket_k(
    const int* __restrict__ esrc, const int* __restrict__ edst,
    int E, int Etot, int NB, const int* __restrict__ scanned,
    unsigned int* __restrict__ gbucket) {
    __shared__ int cur[BKTS];
    for (int b = threadIdx.x; b < BKTS; b += 256)
        cur[b] = scanned[b * NB + blockIdx.x];
    __syncthreads();
    const int e0 = blockIdx.x * CHUNK;
    const int e1 = min(e0 + CHUNK, Etot);
    for (int i = e0 + threadIdx.x; i < e1; i += 256) {
        int s, d;
        if (i < E) { s = esrc[i]; d = edst[i]; }
        else       { s = i - E;   d = i - E; }
        int pos = atomicAdd(&cur[d >> NODE_SHIFT], 1);
        gbucket[pos] = ((unsigned)(d & 127) << 16) | (unsigned)s;
    }
}

__global__ __launch_bounds__(256) void finalize_k(
    const unsigned int* __restrict__ gbucket, const int* __restrict__ scanned,
    int NB, int Etot, unsigned short* __restrict__ ssrc,
    int* __restrict__ rowptr, int Nn) {
    const int b = blockIdx.x;
    const int base = scanned[b * NB];
    const int end = (b + 1 < BKTS) ? scanned[(b + 1) * NB] : Etot;
    const int cnt = end - base;
    const int t = threadIdx.x;

    __shared__ unsigned int keys[CAP];
    __shared__ int hist[128], sA[128], cur[128];

    for (int i = t; i < cnt; i += 256) keys[i] = gbucket[base + i];
    if (t < 128) hist[t] = 0;
    __syncthreads();
    for (int i = t; i < cnt; i += 256) atomicAdd(&hist[keys[i] >> 16], 1);
    __syncthreads();
    if (t < 128) sA[t] = hist[t];
    __syncthreads();
    for (int off = 1; off < 128; off <<= 1) {
        int u = 0;
        if (t < 128 && t >= off) u = sA[t - off];
        __syncthreads();
        if (t < 128) sA[t] += u;
        __syncthreads();
    }
    if (t < 128) {
        int excl = sA[t] - hist[t];
        cur[t] = excl;
        int node = b * 128 + t;
        if (node <= Nn) rowptr[node] = base + excl;
    }
    __syncthreads();
    for (int i = t; i < cnt; i += 256) {
        unsigned k = keys[i];
        int p = atomicAdd(&cur[k >> 16], 1);
        ssrc[base + p] = (unsigned short)(k & 0xFFFFu);
    }
}

__global__ void rowptr_tail_k(int* __restrict__ rowptr, int Nn, int Etot) {
    if (blockIdx.x == 0 && threadIdx.x == 0) rowptr[Nn] = Etot;
}

// ---- layer 1: fused online-softmax aggregation + bias/BN/ELU, bf16 out ----
// H=4, C=32, HC=128. One wave/node; 2 edges per iter (half-waves of 32),
// each lane owns 4 channels (bf16x4 gather). Shuffle-merge the two halves.
__global__ __launch_bounds__(256) void agg1_k(
    const int* __restrict__ rowptr, const unsigned short* __restrict__ ssrc,
    const __hip_bfloat16* __restrict__ xw,
    const float* __restrict__ a_s, const float* __restrict__ a_d,
    const float* __restrict__ bias,
    const float* __restrict__ gamma, const float* __restrict__ beta,
    const float* __restrict__ mean, const float* __restrict__ var,
    __hip_bfloat16* __restrict__ out, int Nn) {
    int n = (blockIdx.x * blockDim.x + threadIdx.x) >> 6;
    int lane = threadIdx.x & 63;
    if (n >= Nn) return;
    const int r0 = rowptr[n];
    const int deg = rowptr[n + 1] - r0;
    const int g = lane >> 5, q = lane & 31;
    const int h = q >> 3;          // head of this lane's channels
    const int c0 = q * 4;          // channel base within HC=128
    const float adh = a_d[n * 4 + h];

    float m = -1e30f, ssum = 0.f;
    float acc0 = 0.f, acc1 = 0.f, acc2 = 0.f, acc3 = 0.f;
#pragma unroll 2
    for (int j = 0; j < deg; j += 2) {
        int jj = j + g;
        bool ok = jj < deg;
        int sid = ssrc[r0 + (ok ? jj : j)];
        float e = a_s[sid * 4 + h] + adh;
        e = (e > 0.f) ? e : 0.2f * e;
        float mn = fmaxf(m, e);
        float scale = __expf(m - mn);
        float p = ok ? __expf(e - mn) : 0.f;
        m = mn;
        ssum = ssum * scale + p;
        bf16x4 f = *(const bf16x4*)(xw + (size_t)sid * 128 + c0);
        acc0 = acc0 * scale + p * (float)f[0];
        acc1 = acc1 * scale + p * (float)f[1];
        acc2 = acc2 * scale + p * (float)f[2];
        acc3 = acc3 * scale + p * (float)f[3];
    }
    // merge the two half-wave states (same channels, disjoint edges)
    {
        float m2 = __shfl_xor(m, 32);
        float s2 = __shfl_xor(ssum, 32);
        float b0 = __shfl_xor(acc0, 32), b1 = __shfl_xor(acc1, 32);
        float b2 = __shfl_xor(acc2, 32), b3 = __shfl_xor(acc3, 32);
        float mn = fmaxf(m, m2);
        float fs = __expf(m - mn), fo = __expf(m2 - mn);
        ssum = ssum * fs + s2 * fo;
        acc0 = acc0 * fs + b0 * fo;
        acc1 = acc1 * fs + b1 * fo;
        acc2 = acc2 * fs + b2 * fo;
        acc3 = acc3 * fs + b3 * fo;
    }
    if (g == 0) {
        const float inv = 1.f / (ssum + 1e-16f);
        float4 bi = *(const float4*)(bias + c0);
        float4 me = *(const float4*)(mean + c0);
        float4 va = *(const float4*)(var + c0);
        float4 ga = *(const float4*)(gamma + c0);
        float4 be = *(const float4*)(beta + c0);
        float v0 = acc0 * inv + bi.x, v1 = acc1 * inv + bi.y;
        float v2 = acc2 * inv + bi.z, v3 = acc3 * inv + bi.w;
        v0 = (v0 - me.x) * rsqrtf(va.x + 1e-5f) * ga.x + be.x;
        v1 = (v1 - me.y) * rsqrtf(va.y + 1e-5f) * ga.y + be.y;
        v2 = (v2 - me.z) * rsqrtf(va.z + 1e-5f) * ga.z + be.z;
        v3 = (v3 - me.w) * rsqrtf(va.w + 1e-5f) * ga.w + be.w;
        v0 = (v0 > 0.f) ? v0 : (__expf(v0) - 1.f);
        v1 = (v1 > 0.f) ? v1 : (__expf(v1) - 1.f);
        v2 = (v2 > 0.f) ? v2 : (__expf(v2) - 1.f);
        v3 = (v3 > 0.f) ? v3 : (__expf(v3) - 1.f);
        bf16x4 o;
        o[0] = (__bf16)v0; o[1] = (__bf16)v1; o[2] = (__bf16)v2; o[3] = (__bf16)v3;
        *(bf16x4*)(out + (size_t)n * 128 + c0) = o;
    }
}

// ---- layer 2: fused online-softmax aggregation + bias, fp32 out -----------
// H=1, C=64. One wave/node; 4 edges per iter (quarter-waves of 16),
// each lane owns 4 channels (bf16x4 gather). Two shuffle-merge rounds.
__global__ __launch_bounds__(256) void agg2_k(
    const int* __restrict__ rowptr, const unsigned short* __restrict__ ssrc,
    const __hip_bfloat16* __restrict__ xw,
    const float* __restrict__ a_s, const float* __restrict__ a_d,
    const float* __restrict__ bias, float* __restrict__ out, int Nn) {
    int n = (blockIdx.x * blockDim.x + threadIdx.x) >> 6;
    int lane = threadIdx.x & 63;
    if (n >= Nn) return;
    const int r0 = rowptr[n];
    const int deg = rowptr[n + 1] - r0;
    const int g = lane >> 4, q = lane & 15;
    const int c0 = q * 4;
    const float adn = a_d[n];

    float m = -1e30f, ssum = 0.f;
    float acc0 = 0.f, acc1 = 0.f, acc2 = 0.f, acc3 = 0.f;
#pragma unroll 2
    for (int j = 0; j < deg; j += 4) {
        int jj = j + g;
        bool ok = jj < deg;
        int sid = ssrc[r0 + (ok ? jj : j)];
        float e = a_s[sid] + adn;
        e = (e > 0.f) ? e : 0.2f * e;
        float mn = fmaxf(m, e);
        float scale = __expf(m - mn);
        float p = ok ? __expf(e - mn) : 0.f;
        m = mn;
        ssum = ssum * scale + p;
        bf16x4 f = *(const bf16x4*)(xw + (size_t)sid * 64 + c0);
        acc0 = acc0 * scale + p * (float)f[0];
        acc1 = acc1 * scale + p * (float)f[1];
        acc2 = acc2 * scale + p * (float)f[2];
        acc3 = acc3 * scale + p * (float)f[3];
    }
#pragma unroll
    for (int off = 16; off <= 32; off <<= 1) {
        float m2 = __shfl_xor(m, off);
        float s2 = __shfl_xor(ssum, off);
        float b0 = __shfl_xor(acc0, off), b1 = __shfl_xor(acc1, off);
        float b2 = __shfl_xor(acc2, off), b3 = __shfl_xor(acc3, off);
        float mn = fmaxf(m, m2);
        float fs = __expf(m - mn), fo = __expf(m2 - mn);
        ssum = ssum * fs + s2 * fo;
        acc0 = acc0 * fs + b0 * fo;
        acc1 = acc1 * fs + b1 * fo;
        acc2 = acc2 * fs + b2 * fo;
        acc3 = acc3 * fs + b3 * fo;
        m = mn;
    }
    if (lane < 16) {
        const float inv = 1.f / (ssum + 1e-16f);
        float4 bi = *(const float4*)(bias + c0);
        float4 o = make_float4(acc0 * inv + bi.x, acc1 * inv + bi.y,
                               acc2 * inv + bi.z, acc3 * inv + bi.w);
        *(float4*)(out + (size_t)n * 64 + c0) = o;
    }
}

extern "C" void kernel_launch(void* const* d_in, const int* in_sizes, int n_in,
                              void* d_out, int out_size, void* d_ws, size_t ws_size,
                              hipStream_t stream) {
    const float* x     = (const float*)d_in[0];
    const int*   ei    = (const int*)d_in[1];
    const float* W1    = (const float*)d_in[2];
    const float* as1   = (const float*)d_in[3];
    const float* ad1   = (const float*)d_in[4];
    const float* b1    = (const float*)d_in[5];
    const float* gamma = (const float*)d_in[6];
    const float* beta  = (const float*)d_in[7];
    const float* mean  = (const float*)d_in[8];
    const float* var   = (const float*)d_in[9];
    const float* W2    = (const float*)d_in[10];
    const float* as2   = (const float*)d_in[11];
    const float* ad2   = (const float*)d_in[12];
    const float* b2    = (const float*)d_in[13];
    float* out = (float*)d_out;

    const int N = NNODES;
    const int E = in_sizes[1] / 2;
    const int Etot = E + N;
    const int* esrc = ei;
    const int* edst = ei + E;

    const int NB = (Etot + CHUNK - 1) / CHUNK;
    const int flatN = BKTS * NB;

    // workspace layout (16-B aligned segments), ~45 MB total
    char* w = (char*)d_ws;
    __hip_bfloat16* xw1 = (__hip_bfloat16*)w; w += (size_t)N * 128 * 2;   // 12.8 MB
    __hip_bfloat16* hbuf = (__hip_bfloat16*)w; w += (size_t)N * 128 * 2;  // 12.8 MB
    __hip_bfloat16* xw2 = (__hip_bfloat16*)w; w += (size_t)N * 64 * 2;    // 6.4 MB
    float* a_s1 = (float*)w; w += (size_t)N * 4 * 4;   // also a_s2 (reuse)
    float* a_d1 = (float*)w; w += (size_t)N * 4 * 4;   // also a_d2 (reuse)
    unsigned int* gbucket = (unsigned int*)w; w += (size_t)Etot * 4 + 16; // 6.6 MB
    int* g_hist  = (int*)w;  w += (size_t)flatN * 4 + 16;
    int* partial = (int*)w;  w += (size_t)flatN * 4 + 16;
    int* scanned = (int*)w;  w += (size_t)(flatN + 4) * 4 + 16;
    int* bsum    = (int*)w;  w += 1024;
    int* rowptr  = (int*)w;  w += (size_t)(N + 8) * 4;
    unsigned short* ssrc_s = (unsigned short*)w; w += (size_t)Etot * 2 + 16; // 3.3 MB
    __hip_bfloat16* wp1 = (__hip_bfloat16*)w; w += 8 * 4 * 64 * 8 * 2;  // 32 KB
    __hip_bfloat16* wp2 = (__hip_bfloat16*)w; w += 4 * 4 * 64 * 8 * 2;  // 16 KB
    float* a_s2 = a_s1; float* a_d2 = a_d1;

    const int TB = 256;
    const int nb2 = (flatN + 255) / 256;
    const int aggBlocks  = (N + 3) / 4;            // one wave/node, 4 waves/block
    const int gemmBlocks = (N / 16 + 3) / 4;       // 3125 row-tiles / 4 waves

    // ---- W repack (independent) ----
    wpack_k<128><<<(8 * 4 * 64 + TB - 1) / TB, TB, 0, stream>>>(W1, wp1);
    wpack_k<64><<<(4 * 4 * 64 + TB - 1) / TB, TB, 0, stream>>>(W2, wp2);

    // ---- CSR build: bucketed counting sort ----
    hist_bucket_k<<<NB, TB, 0, stream>>>(edst, E, Etot, NB, g_hist);
    scan1_k<<<nb2, TB, 0, stream>>>(g_hist, partial, bsum, flatN);
    scan2_k<<<1, TB, 0, stream>>>(bsum, nb2);
    scan3_k<<<nb2, TB, 0, stream>>>(partial, bsum, scanned, flatN);
    scatter_bucket_k<<<NB, TB, 0, stream>>>(esrc, edst, E, Etot, NB, scanned, gbucket);
    finalize_k<<<BKTS, TB, 0, stream>>>(gbucket, scanned, NB, Etot, ssrc_s, rowptr, N);
    rowptr_tail_k<<<1, 64, 0, stream>>>(rowptr, N, Etot);

    // ---- layer 1 ----
    gemm_mfma_k<128, false><<<gemmBlocks, TB, 0, stream>>>(x, wp1, xw1, N);
    attn_scores_k<4, 32><<<(N * 4 + TB - 1) / TB, TB, 0, stream>>>(xw1, as1, ad1, a_s1, a_d1, N * 4);
    agg1_k<<<aggBlocks, TB, 0, stream>>>(rowptr, ssrc_s, xw1, a_s1, a_d1,
                                         b1, gamma, beta, mean, var, hbuf, N);

    // ---- layer 2 ----
    gemm_mfma_k<64, true><<<gemmBlocks, TB, 0, stream>>>(hbuf, wp2, xw2, N);
    attn_scores_k<1, 64><<<(N + TB - 1) / TB, TB, 0, stream>>>(xw2, as2, ad2, a_s2, a_d2, N);
    agg2_k<<<aggBlocks, TB, 0, stream>>>(rowptr, ssrc_s, xw2, a_s2, a_d2, b2, out, N);
}